// Round 4
// baseline (1221.795 us; speedup 1.0000x reference)
//
#include <hip/hip_runtime.h>
#include <hip/hip_fp16.h>
#include <math.h>

#define B_    8
#define CDIM  256
#define HH    256
#define WW    32
#define PP    8192
#define HEADS 8
#define FFI   1024

typedef _Float16 f16;
typedef _Float16 half8 __attribute__((ext_vector_type(8)));
typedef _Float16 half4 __attribute__((ext_vector_type(4)));
typedef _Float16 f16x2v __attribute__((ext_vector_type(2)));
typedef float f32x4 __attribute__((ext_vector_type(4)));

// ---------------- workspace layout (float offsets) ----------------
static const size_t OFF_QPROBE = 16908288;
static const size_t OFF_SH     = 16910336;
static const size_t OFF_IH     = 16912384;
static const size_t OFF_IW     = 16912896;
static const size_t OFF_STM    = 16913408;
static const size_t OFF_STR    = 16921600;
static const size_t OFF_VSEL   = 16929792;
static const size_t OFF_W16    = 17060864;   // 917504 halves = 458752 floats

// fp16 weight region offsets (in halves)
#define WH_QKV  0
#define WH_OUT  196608
#define WH_COMB 262144
#define WH_FF1  393216
#define WH_FF2  655360

// fast gelu: x*Phi(x) via A&S 7.1.26 erf, |erf err| <= 1.5e-7, branchless.
__device__ __forceinline__ float gelu_f(float x) {
  float z = fabsf(x) * 0.70710678118f;
  float t = __builtin_amdgcn_rcpf(1.0f + 0.3275911f * z);
  float poly = t * (0.254829592f +
               t * (-0.284496736f +
               t * (1.421413741f +
               t * (-1.453152027f +
               t * 1.061405429f))));
  float e = 1.0f - poly * __expf(-z * z);
  return 0.5f * x * (1.0f + copysignf(e, x));
}

// ---------------- weights -> fp16 ----------------
__global__ __launch_bounds__(256) void k_wcvt(const float* __restrict__ s0,
                                              const float* __restrict__ s1,
                                              const float* __restrict__ s2,
                                              const float* __restrict__ s3,
                                              const float* __restrict__ s4,
                                              f16* __restrict__ dst) {
  int blk = blockIdx.x;   // 896 blocks x 1024 elems
  const float* src; size_t base;
  if (blk < 192)      { src = s0; base = WH_QKV;  }
  else if (blk < 256) { src = s1; base = WH_OUT;  blk -= 192; }
  else if (blk < 384) { src = s2; base = WH_COMB; blk -= 256; }
  else if (blk < 640) { src = s3; base = WH_FF1;  blk -= 384; }
  else                { src = s4; base = WH_FF2;  blk -= 640; }
  int off = blk * 1024 + threadIdx.x * 4;
  float4 v = *(const float4*)(src + off);
  half4 h; h[0] = (f16)v.x; h[1] = (f16)v.y; h[2] = (f16)v.z; h[3] = (f16)v.w;
  *(half4*)(dst + base + off) = h;
}

// ---------------- fused channel-LN -> xn fp16 ----------------
__global__ __launch_bounds__(256) void k_lnxn(const float* __restrict__ x,
                                              const float* __restrict__ g,
                                              const float* __restrict__ bb,
                                              f16* __restrict__ xn) {
  int idx = blockIdx.x * 256 + threadIdx.x;      // 65536 = b*PP + p
  int b = idx >> 13, p = idx & 8191;
  const float* xp = x + (size_t)b * CDIM * PP + p;
  float s = 0.f, s2 = 0.f;
  for (int c = 0; c < CDIM; c++) { float v = xp[(size_t)c * PP]; s += v; s2 += v * v; }
  float m = s * (1.0f / CDIM);
  float var = s2 * (1.0f / CDIM) - m * m;
  float r = rsqrtf(var + 1e-5f);
  f16* xo = xn + (size_t)b * CDIM * PP + p;
  for (int c = 0; c < CDIM; c++)
    xo[(size_t)c * PP] = (f16)((xp[(size_t)c * PP] - m) * r * g[c] + bb[c]);
}

// ================= MFMA fp16 GEMM, 1-m-tile variant (FF2 float-out only) =================
#define MF_STAGE                                                                   \
  int t = threadIdx.x;                                                             \
  int nw_ = gridDim.x * gridDim.y;                                                 \
  int hb_ = blockIdx.x + gridDim.x * blockIdx.y;                                   \
  int wk_ = (hb_ & 7) * (nw_ >> 3) + (hb_ >> 3);                                   \
  int gy_ = gridDim.y;                                                             \
  int sh_ = __ffs(gy_) - 1;                                                        \
  int p0 = (wk_ >> sh_) * 128, m0 = (wk_ & (gy_ - 1)) * 128, z = blockIdx.z;       \
  int lane = t & 63, wave = t >> 6;                                                \
  int wm = (wave >> 1) * 64, wp = (wave & 1) * 64;                                 \
  int col = lane & 15, quad = lane >> 4;                                           \
  f32x4 acc[4][4];                                                                 \
  _Pragma("unroll") for (int i = 0; i < 4; i++)                                    \
  _Pragma("unroll") for (int j = 0; j < 4; j++)                                    \
      acc[i][j] = (f32x4){0.f, 0.f, 0.f, 0.f};                                     \
  int am = t >> 1, ak = (t & 1) * 16;                                              \
  int bp = (t & 15) * 8, bk = (t >> 4) * 2;                                        \
  int erot = t & 7;                                                                \
  const f16* wr0 = W + (size_t)(m0 + am) * K + ak;                                 \
  const f16* br0 = inB + (size_t)bk * PP + p0 + bp;                                \
  half8 w0 = *(const half8*)wr0;                                                   \
  half8 w1 = *(const half8*)(wr0 + 8);                                             \
  half8 r0 = *(const half8*)br0;                                                   \
  half8 r1 = *(const half8*)(br0 + PP);                                            \
  for (int k0 = 0; k0 < K; k0 += 32) {                                             \
    *(half8*)&As[am][ak] = w0;                                                     \
    *(half8*)&As[am][ak + 8] = w1;                                                 \
    _Pragma("unroll") for (int e0 = 0; e0 < 8; e0++) {                             \
      int e = (e0 + erot) & 7;                                                     \
      f16x2v pr2; pr2[0] = r0[e]; pr2[1] = r1[e];                                  \
      *(f16x2v*)&Bs[bp + e][bk] = pr2;                                             \
    }                                                                              \
    __syncthreads();                                                               \
    int kn = (k0 + 32 < K) ? k0 + 32 : k0;                                         \
    w0 = *(const half8*)(wr0 + kn);                                                \
    w1 = *(const half8*)(wr0 + kn + 8);                                            \
    r0 = *(const half8*)(inB + (size_t)(kn + bk) * PP + p0 + bp);                  \
    r1 = *(const half8*)(inB + (size_t)(kn + bk + 1) * PP + p0 + bp);              \
    half8 af[4], bf[4];                                                            \
    _Pragma("unroll") for (int i = 0; i < 4; i++)                                  \
      af[i] = *(const half8*)&As[wm + i * 16 + col][quad * 8];                     \
    _Pragma("unroll") for (int j = 0; j < 4; j++)                                  \
      bf[j] = *(const half8*)&Bs[wp + j * 16 + col][quad * 8];                     \
    _Pragma("unroll") for (int i = 0; i < 4; i++)                                  \
    _Pragma("unroll") for (int j = 0; j < 4; j++)                                  \
        acc[i][j] = __builtin_amdgcn_mfma_f32_16x16x32_f16(af[i], bf[j],           \
                                                           acc[i][j], 0, 0, 0);    \
    __syncthreads();                                                               \
  }

__global__ __launch_bounds__(256) void k_mf(const f16* __restrict__ W,
                                            const f16* __restrict__ In, size_t inZ,
                                            f16* __restrict__ OutH,
                                            float* __restrict__ OutF, size_t outZ,
                                            const float* __restrict__ bias,
                                            const float* __restrict__ resid, size_t residZ,
                                            int K) {
  __shared__ f16 As[128][40];
  __shared__ f16 Bs[128][40];
  const f16* inB = In + (size_t)blockIdx.z * inZ;
  MF_STAGE
#pragma unroll
  for (int i = 0; i < 4; i++) {
    int mb = m0 + wm + i * 16 + quad * 4;
#pragma unroll
    for (int r = 0; r < 4; r++) {
      int m = mb + r;
      float bs = bias ? bias[m] : 0.f;
#pragma unroll
      for (int j = 0; j < 4; j++) {
        int p = p0 + wp + j * 16 + col;
        float v = acc[i][j][r] + bs;
        size_t off = (size_t)z * outZ + (size_t)m * PP + p;
        if (resid) v += resid[(size_t)z * residZ + (size_t)m * PP + p];
        if (OutF) OutF[off] = v;
        else OutH[off] = (f16)v;
      }
    }
  }
}

// ================= 2-m-tile MFMA GEMM: 256m x 128p per block =================
// Shares the In panel across two weight slices (halves In traffic, doubles
// MFMA per load-wait) + LDS-staged coalesced half8 epilogue.
#define MF_STAGE2                                                                  \
  int t = threadIdx.x;                                                             \
  int nw_ = gridDim.x * gridDim.y;                                                 \
  int hb_ = blockIdx.x + gridDim.x * blockIdx.y;                                   \
  int wk_ = (hb_ & 7) * (nw_ >> 3) + (hb_ >> 3);                                   \
  int gy_ = gridDim.y;                                                             \
  int sh_ = __ffs(gy_) - 1;                                                        \
  int p0 = (wk_ >> sh_) * 128, m0 = (wk_ & (gy_ - 1)) * 256, z = blockIdx.z;       \
  int lane = t & 63, wave = t >> 6;                                                \
  int wm = (wave >> 1) * 64, wp = (wave & 1) * 64;                                 \
  int col = lane & 15, quad = lane >> 4;                                           \
  f32x4 acc[2][4][4];                                                              \
  _Pragma("unroll") for (int mt = 0; mt < 2; mt++)                                 \
  _Pragma("unroll") for (int i = 0; i < 4; i++)                                    \
  _Pragma("unroll") for (int j = 0; j < 4; j++)                                    \
      acc[mt][i][j] = (f32x4){0.f, 0.f, 0.f, 0.f};                                 \
  int am = t >> 1, ak = (t & 1) * 16;                                              \
  int bp = (t & 15) * 8, bk = (t >> 4) * 2;                                        \
  int erot = t & 7;                                                                \
  const f16* wr0 = W + (size_t)(m0 + am) * K + ak;                                 \
  const f16* wr1 = wr0 + (size_t)128 * K;                                          \
  const f16* br0 = inB + (size_t)bk * PP + p0 + bp;                                \
  half8 w0 = *(const half8*)wr0;                                                   \
  half8 w1 = *(const half8*)(wr0 + 8);                                             \
  half8 w2 = *(const half8*)wr1;                                                   \
  half8 w3 = *(const half8*)(wr1 + 8);                                             \
  half8 r0 = *(const half8*)br0;                                                   \
  half8 r1 = *(const half8*)(br0 + PP);                                            \
  for (int k0 = 0; k0 < K; k0 += 32) {                                             \
    *(half8*)&As[am][ak] = w0;                                                     \
    *(half8*)&As[am][ak + 8] = w1;                                                 \
    *(half8*)&As[128 + am][ak] = w2;                                               \
    *(half8*)&As[128 + am][ak + 8] = w3;                                           \
    _Pragma("unroll") for (int e0 = 0; e0 < 8; e0++) {                             \
      int e = (e0 + erot) & 7;                                                     \
      f16x2v pr2; pr2[0] = r0[e]; pr2[1] = r1[e];                                  \
      *(f16x2v*)&Bs[bp + e][bk] = pr2;                                             \
    }                                                                              \
    __syncthreads();                                                               \
    int kn = (k0 + 32 < K) ? k0 + 32 : k0;                                         \
    w0 = *(const half8*)(wr0 + kn);                                                \
    w1 = *(const half8*)(wr0 + kn + 8);                                            \
    w2 = *(const half8*)(wr1 + kn);                                                \
    w3 = *(const half8*)(wr1 + kn + 8);                                            \
    r0 = *(const half8*)(inB + (size_t)(kn + bk) * PP + p0 + bp);                  \
    r1 = *(const half8*)(inB + (size_t)(kn + bk + 1) * PP + p0 + bp);              \
    half8 bf[4];                                                                   \
    _Pragma("unroll") for (int j = 0; j < 4; j++)                                  \
      bf[j] = *(const half8*)&Bs[wp + j * 16 + col][quad * 8];                     \
    _Pragma("unroll") for (int mt = 0; mt < 2; mt++) {                             \
      half8 af[4];                                                                 \
      _Pragma("unroll") for (int i = 0; i < 4; i++)                                \
        af[i] = *(const half8*)&As[mt * 128 + wm + i * 16 + col][quad * 8];        \
      _Pragma("unroll") for (int i = 0; i < 4; i++)                                \
      _Pragma("unroll") for (int j = 0; j < 4; j++)                                \
          acc[mt][i][j] = __builtin_amdgcn_mfma_f32_16x16x32_f16(af[i], bf[j],     \
                                                         acc[mt][i][j], 0, 0, 0); \
    }                                                                              \
    __syncthreads();                                                               \
  }

__global__ __launch_bounds__(256) void k_mf2(const f16* __restrict__ W,
                                             const f16* __restrict__ In, size_t inZ,
                                             f16* __restrict__ OutH, size_t outZ,
                                             const float* __restrict__ bias,
                                             const float* __restrict__ resid, size_t residZ,
                                             int K) {
  __shared__ f16 As[256][40];
  __shared__ f16 Bs[128][40];
  const f16* inB = In + (size_t)blockIdx.z * inZ;
  MF_STAGE2
  // ---- LDS-staged coalesced epilogue: 4 passes of 64 rows x 128 cols ----
  f16 (*ebuf)[136] = (f16(*)[136])&As[0][0];   // 64*136*2 = 17408 B <= As
#pragma unroll
  for (int mt = 0; mt < 2; mt++) {
#pragma unroll
    for (int half = 0; half < 2; half++) {
      __syncthreads();
      if (wm == half * 64) {
#pragma unroll
        for (int i = 0; i < 4; i++) {
#pragma unroll
          for (int r = 0; r < 4; r++) {
            int lr = i * 16 + quad * 4 + r;
            int m = m0 + mt * 128 + half * 64 + lr;
            float bs = bias ? bias[m] : 0.f;
#pragma unroll
            for (int j = 0; j < 4; j++) {
              float v = acc[mt][i][j][r] + bs;
              if (resid)
                v += resid[(size_t)z * residZ + (size_t)m * PP + p0 + wp + j * 16 + col];
              ebuf[lr][wp + j * 16 + col] = (f16)v;
            }
          }
        }
      }
      __syncthreads();
#pragma unroll
      for (int u = 0; u < 4; u++) {
        int idx = u * 256 + t;
        int row = idx >> 4, seg = idx & 15;
        int m = m0 + mt * 128 + half * 64 + row;
        *(half8*)(OutH + (size_t)z * outZ + (size_t)m * PP + p0 + seg * 8) =
            *(const half8*)&ebuf[row][seg * 8];
      }
    }
  }
}

// qk GEMM (2-m-tile): epilogue l2-normalizes groups of 32 consecutive p, stores fp16
__global__ __launch_bounds__(256) void k_mf_qk2(const f16* __restrict__ W,
                                                const f16* __restrict__ In, size_t inZ,
                                                f16* __restrict__ qkO, int K) {
  __shared__ f16 As[256][40];
  __shared__ f16 Bs[128][40];
  const f16* inB = In + (size_t)blockIdx.z * inZ;
  MF_STAGE2
  f16 (*ebuf)[136] = (f16(*)[136])&As[0][0];
#pragma unroll
  for (int mt = 0; mt < 2; mt++) {
#pragma unroll
    for (int half = 0; half < 2; half++) {
      __syncthreads();
      if (wm == half * 64) {
#pragma unroll
        for (int i = 0; i < 4; i++) {
#pragma unroll
          for (int r = 0; r < 4; r++) {
            int lr = i * 16 + quad * 4 + r;
#pragma unroll
            for (int jp = 0; jp < 2; jp++) {
              float a0 = acc[mt][i][2 * jp][r], a1 = acc[mt][i][2 * jp + 1][r];
              float ss = a0 * a0 + a1 * a1;
              ss += __shfl_xor(ss, 1);
              ss += __shfl_xor(ss, 2);
              ss += __shfl_xor(ss, 4);
              ss += __shfl_xor(ss, 8);
              float inv = 1.0f / fmaxf(sqrtf(ss), 1e-12f);
              ebuf[lr][wp + 2 * jp * 16 + col] = (f16)(a0 * inv);
              ebuf[lr][wp + 2 * jp * 16 + col + 16] = (f16)(a1 * inv);
            }
          }
        }
      }
      __syncthreads();
#pragma unroll
      for (int u = 0; u < 4; u++) {
        int idx = u * 256 + t;
        int row = idx >> 4, seg = idx & 15;
        int m = m0 + mt * 128 + half * 64 + row;
        *(half8*)(qkO + (size_t)z * 512 * PP + (size_t)m * PP + p0 + seg * 8) =
            *(const half8*)&ebuf[row][seg * 8];
      }
    }
  }
}

// ---------------- q_probe + sh scores (vectorized) ----------------
__global__ __launch_bounds__(256) void k_probe(const f16* __restrict__ qk,
                                               float* __restrict__ qprobe,
                                               float* __restrict__ sh) {
  __shared__ float red[64][32];
  __shared__ float qp[32];
  __shared__ float ksum[32][32];
  int bh = blockIdx.x, b = bh >> 3, hd = bh & 7;
  int t = threadIdx.x;
  const f16* qb = qk + ((size_t)(b * 512 + hd * 32)) * PP;
  {
    int g = t >> 2, wq = (t & 3) * 8;
    float s[8];
#pragma unroll
    for (int e = 0; e < 8; e++) s[e] = 0.f;
    for (int it = 0; it < 128; it++) {
      int row = g * 128 + it;
      half8 v = *(const half8*)(qb + (size_t)(row >> 8) * PP + (row & 255) * 32 + wq);
#pragma unroll
      for (int e = 0; e < 8; e++) s[e] += (float)v[e];
    }
#pragma unroll
    for (int e = 0; e < 8; e++) red[g][wq + e] = s[e];
  }
  __syncthreads();
  if (t < 32) {
    float a = 0.f;
    for (int g = 0; g < 64; g++) a += red[g][t];
    qp[t] = a;
    qprobe[bh * 32 + t] = a;
  }
  const f16* kb = qk + ((size_t)(b * 512 + 256 + hd * 32)) * PP;
  {
    int d = t >> 3, wq = (t & 7) * 4;
    float s[4] = {0.f, 0.f, 0.f, 0.f};
    for (int h = 0; h < 256; h++) {
      half4 v = *(const half4*)(kb + (size_t)d * PP + h * 32 + wq);
#pragma unroll
      for (int e = 0; e < 4; e++) s[e] += (float)v[e];
    }
#pragma unroll
    for (int e = 0; e < 4; e++) ksum[d][wq + e] = s[e];
  }
  __syncthreads();
  if (t < 32) {
    float a = 0.f;
    for (int w = 0; w < 32; w++) a += qp[w] * ksum[t][w];
    sh[bh * 32 + t] = a;
  }
}

__global__ __launch_bounds__(64) void k_topk_h(const float* __restrict__ sh, int* __restrict__ ih) {
  int bh = blockIdx.x;
  if (threadIdx.x != 0) return;
  float v[32];
#pragma unroll
  for (int i = 0; i < 32; i++) v[i] = sh[bh * 32 + i];
  for (int s = 0; s < 8; s++) {
    int bi = 0; float bv = v[0];
#pragma unroll
    for (int i = 1; i < 32; i++) { if (v[i] > bv) { bv = v[i]; bi = i; } }
    ih[bh * 8 + s] = bi;
    v[bi] = -3.4e38f;
  }
}

__global__ __launch_bounds__(256) void k_sw_topk(const f16* __restrict__ qk,
                                                 const float* __restrict__ qprobe,
                                                 const int* __restrict__ ih,
                                                 int* __restrict__ iw) {
  __shared__ float qp[32];
  __shared__ float sw[256];
  __shared__ int ihs[8];
  int bh = blockIdx.x, b = bh >> 3, hd = bh & 7;
  int t = threadIdx.x;
  if (t < 32) qp[t] = qprobe[bh * 32 + t];
  if (t < 8) ihs[t] = ih[bh * 8 + t];
  __syncthreads();
  const f16* kb = qk + ((size_t)(b * 512 + 256 + hd * 32)) * PP;
  float s = 0.f;
  for (int a = 0; a < 8; a++) {
    const f16* kd = kb + (size_t)ihs[a] * PP + t * 32;
#pragma unroll
    for (int w = 0; w < 32; w++) s += qp[w] * (float)kd[w];
  }
  sw[t] = s;
  __syncthreads();
  if (t == 0) {
    for (int sel = 0; sel < 8; sel++) {
      int bi = 0; float bv = sw[0];
      for (int i = 1; i < 256; i++) { if (sw[i] > bv) { bv = sw[i]; bi = i; } }
      iw[bh * 8 + sel] = bi;
      sw[bi] = -3.4e38f;
    }
  }
}

// ---------------- v at selected positions, LDS-staged from xn fp16 ----------------
__global__ __launch_bounds__(256) void k_vsel2(const f16* __restrict__ xn,
                                               const f16* __restrict__ W16,
                                               const int* __restrict__ ih,
                                               const int* __restrict__ iw,
                                               float* __restrict__ vsel) {
  __shared__ f16 xg[64][264];
  __shared__ float wrow[8][64];
  __shared__ int ihs[8], iws8[8];
  int bh = blockIdx.x, b = bh >> 3, hd = bh & 7;
  int t = threadIdx.x;
  if (t < 8) { ihs[t] = ih[bh * 8 + t]; iws8[t] = iw[bh * 8 + t]; }
  __syncthreads();
  float acc[8];
#pragma unroll
  for (int a = 0; a < 8; a++) acc[a] = 0.f;
  for (int c0 = 0; c0 < 256; c0 += 64) {
    for (int rep = 0; rep < 2; rep++) {
      int cc = rep * 32 + (t >> 3);
      int seg = t & 7;
#pragma unroll
      for (int u = 0; u < 4; u++) {
        int h8 = seg * 4 + u;                 // 0..31
        int bi = h8 >> 2, wq = (h8 & 3) * 8;
        half8 v = *(const half8*)(xn + ((size_t)(b * 256 + c0 + cc)) * PP + iws8[bi] * 32 + wq);
        *(half8*)&xg[cc][h8 * 8] = v;
      }
    }
    for (int rep = 0; rep < 2; rep++) {
      int idx = t + rep * 256;
      int a = idx >> 6, cc = idx & 63;
      wrow[a][cc] = (float)W16[(size_t)(512 + hd * 32 + ihs[a]) * 256 + c0 + cc];
    }
    __syncthreads();
    for (int cc = 0; cc < 64; cc++) {
      float xv = (float)xg[cc][t];
#pragma unroll
      for (int a = 0; a < 8; a++) acc[a] += wrow[a][cc] * xv;
    }
    __syncthreads();
  }
  int bi = t >> 5, w = t & 31;
#pragma unroll
  for (int a = 0; a < 8; a++)
    vsel[((size_t)bh * 64 + a * 8 + bi) * 32 + w] = acc[a];
}

// ---------------- MFMA attention ----------------
__global__ __launch_bounds__(256) void k_attn_mf(const f16* __restrict__ qk,
                                                 const float* __restrict__ vsel,
                                                 const int* __restrict__ ih,
                                                 const int* __restrict__ iw,
                                                 f16* __restrict__ o_r) {
  __shared__ f16 Ks[64][40];
  __shared__ f16 Vt[32][72];
  __shared__ f16 Ps[4][32][72];
  __shared__ f16 Os[32][136];
  __shared__ int ihs[8], iws8[8];
  int bh = blockIdx.y, b = bh >> 3, hd = bh & 7;
  int t = threadIdx.x;
  if (t < 8) { ihs[t] = ih[bh * 8 + t]; iws8[t] = iw[bh * 8 + t]; }
  __syncthreads();
  {
    int j = t >> 2, wc = (t & 3) * 8;
    const f16* kb = qk + ((size_t)(b * 512 + 256 + hd * 32 + ihs[j >> 3])) * PP
                    + iws8[j & 7] * 32 + wc;
    *(half8*)&Ks[j][wc] = *(const half8*)kb;
  }
  for (int rep = 0; rep < 2; rep++) {
    int idx = t + rep * 256;
    int j = idx >> 3, w4 = (idx & 7) * 4;
    float4 v = *(const float4*)(vsel + ((size_t)bh * 64 + j) * 32 + w4);
    Vt[w4 + 0][j] = (f16)v.x; Vt[w4 + 1][j] = (f16)v.y;
    Vt[w4 + 2][j] = (f16)v.z; Vt[w4 + 3][j] = (f16)v.w;
  }
  __syncthreads();
  int wv = t >> 6, lane = t & 63, col = lane & 15, quad = lane >> 4;
  int i0 = blockIdx.x * 128;
  int dq = i0 >> 8;
  int hb = (i0 & 255) + wv * 32;
  const f16* qbase = qk + ((size_t)(b * 512 + hd * 32 + dq)) * PP;
  f32x4 sacc[2][4];
#pragma unroll
  for (int i = 0; i < 2; i++)
#pragma unroll
    for (int j = 0; j < 4; j++) sacc[i][j] = (f32x4){0.f, 0.f, 0.f, 0.f};
#pragma unroll
  for (int mt = 0; mt < 2; mt++) {
    half8 af = *(const half8*)(qbase + (size_t)(hb + mt * 16 + col) * 32 + quad * 8);
#pragma unroll
    for (int nt = 0; nt < 4; nt++) {
      half8 bf = *(const half8*)&Ks[nt * 16 + col][quad * 8];
      sacc[mt][nt] = __builtin_amdgcn_mfma_f32_16x16x32_f16(af, bf, sacc[mt][nt], 0, 0, 0);
    }
  }
#pragma unroll
  for (int mt = 0; mt < 2; mt++) {
#pragma unroll
    for (int r = 0; r < 4; r++) {
      float s0 = sacc[mt][0][r], s1 = sacc[mt][1][r], s2 = sacc[mt][2][r], s3 = sacc[mt][3][r];
      float mx = fmaxf(fmaxf(s0, s1), fmaxf(s2, s3));
      mx = fmaxf(mx, __shfl_xor(mx, 1));
      mx = fmaxf(mx, __shfl_xor(mx, 2));
      mx = fmaxf(mx, __shfl_xor(mx, 4));
      mx = fmaxf(mx, __shfl_xor(mx, 8));
      float e0 = __expf(s0 - mx), e1 = __expf(s1 - mx), e2 = __expf(s2 - mx), e3 = __expf(s3 - mx);
      float l = e0 + e1 + e2 + e3;
      l += __shfl_xor(l, 1);
      l += __shfl_xor(l, 2);
      l += __shfl_xor(l, 4);
      l += __shfl_xor(l, 8);
      float inv = 1.0f / l;
      int row = mt * 16 + quad * 4 + r;
      Ps[wv][row][0 * 16 + col] = (f16)(e0 * inv);
      Ps[wv][row][1 * 16 + col] = (f16)(e1 * inv);
      Ps[wv][row][2 * 16 + col] = (f16)(e2 * inv);
      Ps[wv][row][3 * 16 + col] = (f16)(e3 * inv);
    }
  }
  __syncthreads();
  f32x4 oacc[2][2];
#pragma unroll
  for (int i = 0; i < 2; i++)
#pragma unroll
    for (int j = 0; j < 2; j++) oacc[i][j] = (f32x4){0.f, 0.f, 0.f, 0.f};
#pragma unroll
  for (int kk = 0; kk < 2; kk++) {
    half8 ap[2], bv[2];
#pragma unroll
    for (int mt = 0; mt < 2; mt++) ap[mt] = *(const half8*)&Ps[wv][mt * 16 + col][kk * 32 + quad * 8];
#pragma unroll
    for (int wn = 0; wn < 2; wn++) bv[wn] = *(const half8*)&Vt[wn * 16 + col][kk * 32 + quad * 8];
#pragma unroll
    for (int mt = 0; mt < 2; mt++)
#pragma unroll
      for (int wn = 0; wn < 2; wn++)
        oacc[mt][wn] = __builtin_amdgcn_mfma_f32_16x16x32_f16(ap[mt], bv[wn], oacc[mt][wn], 0, 0, 0);
  }
#pragma unroll
  for (int mt = 0; mt < 2; mt++)
#pragma unroll
    for (int wn = 0; wn < 2; wn++)
#pragma unroll
      for (int r = 0; r < 4; r++)
        Os[wn * 16 + col][wv * 32 + mt * 16 + quad * 4 + r] = (f16)oacc[mt][wn][r];
  __syncthreads();
  {
    int dd = t >> 3, seg = t & 7;
#pragma unroll
    for (int u = 0; u < 2; u++) {
      int io = (seg * 2 + u) * 8;
      *(half8*)(o_r + ((size_t)(b * 256 + hd * 32 + dd)) * PP + i0 + io) = *(const half8*)&Os[dd][io];
    }
  }
}

// ---------------- conv branch dw3x3 on x -> fp16 channels [256,512) of bv512 ----------------
__global__ __launch_bounds__(256) void k_dw(const float* __restrict__ in,
                                            const float* __restrict__ wdw,
                                            const float* __restrict__ bdw,
                                            f16* __restrict__ out) {
  int bc = blockIdx.x;
  int b = bc >> 8, c = bc & 255;
  int p = blockIdx.y * 256 + threadIdx.x;
  int x0 = p >> 5, y0 = p & 31;
  const float* ip = in + (size_t)bc * PP;
  const float* wp = wdw + c * 9;
  float s = bdw[c];
#pragma unroll
  for (int i = 0; i < 3; i++) {
    int xx = x0 + i - 1;
    if (xx < 0 || xx >= HH) continue;
#pragma unroll
    for (int j = 0; j < 3; j++) {
      int yy = y0 + j - 1;
      if (yy < 0 || yy >= WW) continue;
      s += wp[i * 3 + j] * ip[xx * 32 + yy];
    }
  }
  out[((size_t)(b * 512 + 256 + c)) * PP + p] = (f16)s;
}

// ======== fused FF inner: gelu(inorm(h1)) -> dwconv -> gelu(inorm(.)) + residual ========
__global__ __launch_bounds__(256) void k_ff_fused(const f16* __restrict__ h1,
                                                  const float* __restrict__ wdw,
                                                  const float* __restrict__ bdw,
                                                  f16* __restrict__ h2) {
  __shared__ float gbuf[256 * 33];
  __shared__ float redA[8], redB[8];
  int c = blockIdx.x, zz = blockIdx.y;
  int t = threadIdx.x;
  int wv = t >> 6, lane = t & 63;
  const f16* hp = h1 + ((size_t)zz * FFI + c) * PP;
  f16* out = h2 + ((size_t)zz * FFI + c) * PP;

  float v[32];
  float s = 0.f, s2 = 0.f;
#pragma unroll
  for (int u = 0; u < 4; u++) {
    half8 h = *(const half8*)(hp + (u * 256 + t) * 8);
#pragma unroll
    for (int e = 0; e < 8; e++) { float f = (float)h[e]; v[u * 8 + e] = f; s += f; s2 += f * f; }
  }
#pragma unroll
  for (int o = 32; o; o >>= 1) { s += __shfl_xor(s, o); s2 += __shfl_xor(s2, o); }
  if (lane == 0) { redA[wv] = s; redA[4 + wv] = s2; }
  __syncthreads();
  float m = (redA[0] + redA[1] + redA[2] + redA[3]) * (1.0f / PP);
  float s2a = (redA[4] + redA[5] + redA[6] + redA[7]) * (1.0f / PP);
  float r = rsqrtf(s2a - m * m + 1e-5f);

#pragma unroll
  for (int u = 0; u < 4; u++) {
    int base = (u * 256 + t) * 8;
    int row = base >> 5, colb = base & 31;
#pragma unroll
    for (int e = 0; e < 8; e++)
      gbuf[row * 33 + colb + e] = gelu_f((v[u * 8 + e] - m) * r);
  }
  __syncthreads();

  float wf[9];
#pragma unroll
  for (int i = 0; i < 9; i++) wf[i] = wdw[c * 9 + i];
  float bd = bdw[c];
  float g0[32];
#pragma unroll
  for (int y = 0; y < 32; y++) g0[y] = gbuf[t * 33 + y];
  const float* up = (t > 0) ? &gbuf[(t - 1) * 33] : nullptr;
  const float* dn = (t < 255) ? &gbuf[(t + 1) * 33] : nullptr;
  float d[32];
  float sd = 0.f, sd2 = 0.f;
#pragma unroll
  for (int y = 0; y < 32; y++) {
    float um1 = 0.f, u0 = 0.f, up1 = 0.f;
    float dm1 = 0.f, d0 = 0.f, dp1 = 0.f;
    if (up) { u0 = up[y]; if (y > 0) um1 = up[y - 1]; if (y < 31) up1 = up[y + 1]; }
    if (dn) { d0 = dn[y]; if (y > 0) dm1 = dn[y - 1]; if (y < 31) dp1 = dn[y + 1]; }
    float a = bd + wf[1] * u0 + wf[4] * g0[y] + wf[7] * d0;
    if (y > 0)  a += wf[0] * um1 + wf[3] * g0[y - 1] + wf[6] * dm1;
    if (y < 31) a += wf[2] * up1 + wf[5] * g0[y + 1] + wf[8] * dp1;
    d[y] = a; sd += a; sd2 += a * a;
  }
#pragma unroll
  for (int o = 32; o; o >>= 1) { sd += __shfl_xor(sd, o); sd2 += __shfl_xor(sd2, o); }
  if (lane == 0) { redB[wv] = sd; redB[4 + wv] = sd2; }
  __syncthreads();
  float dm = (redB[0] + redB[1] + redB[2] + redB[3]) * (1.0f / PP);
  float dv = (redB[4] + redB[5] + redB[6] + redB[7]) * (1.0f / PP);
  float dr = rsqrtf(dv - dm * dm + 1e-5f);

#pragma unroll
  for (int y = 0; y < 32; y++)
    gbuf[t * 33 + y] = g0[y] + gelu_f((d[y] - dm) * dr);
  __syncthreads();

#pragma unroll
  for (int u = 0; u < 4; u++) {
    int base = (u * 256 + t) * 8;
    int row = base >> 5, colb = base & 31;
    half8 h;
#pragma unroll
    for (int e = 0; e < 8; e++) h[e] = (f16)gbuf[row * 33 + colb + e];
    *(half8*)(out + base) = h;
  }
}

// ---------------- fp32 inorm stats + apply (final) ----------------
__global__ __launch_bounds__(256) void k_istats(const float* __restrict__ in,
                                                float* __restrict__ stm,
                                                float* __restrict__ str) {
  __shared__ float ss[256], ss2[256];
  int row = blockIdx.x, t = threadIdx.x;
  const float* p = in + (size_t)row * PP;
  float s = 0.f, s2 = 0.f;
  for (int i = t; i < PP; i += 256) { float v = p[i]; s += v; s2 += v * v; }
  ss[t] = s; ss2[t] = s2;
  __syncthreads();
  for (int off = 128; off; off >>= 1) {
    if (t < off) { ss[t] += ss[t + off]; ss2[t] += ss2[t + off]; }
    __syncthreads();
  }
  if (t == 0) {
    float m = ss[0] * (1.0f / PP);
    float var = ss2[0] * (1.0f / PP) - m * m;
    stm[row] = m;
    str[row] = rsqrtf(var + 1e-5f);
  }
}

__global__ __launch_bounds__(256) void k_napply(float* __restrict__ io,
                                                const float* __restrict__ stm,
                                                const float* __restrict__ str) {
  size_t idx = (size_t)blockIdx.x * 256 + threadIdx.x;
  int row = (int)(idx >> 13);
  io[idx] = (io[idx] - stm[row]) * str[row];
}

extern "C" void kernel_launch(void* const* d_in, const int* in_sizes, int n_in,
                              void* d_out, int out_size, void* d_ws, size_t ws_size,
                              hipStream_t stream) {
  const float* x      = (const float*)d_in[0];
  const float* cln_g  = (const float*)d_in[1];
  const float* cln_b  = (const float*)d_in[2];
  const float* w_qkv  = (const float*)d_in[3];
  const float* w_out  = (const float*)d_in[4];
  const float* b_out  = (const float*)d_in[5];
  const float* w_dw   = (const float*)d_in[6];
  const float* b_dw   = (const float*)d_in[7];
  const float* w_comb = (const float*)d_in[8];
  const float* b_comb = (const float*)d_in[9];
  const float* w_ff1  = (const float*)d_in[10];
  const float* b_ff1  = (const float*)d_in[11];
  const float* w_ffdw = (const float*)d_in[12];
  const float* b_ffdw = (const float*)d_in[13];
  const float* w_ff2  = (const float*)d_in[14];
  const float* b_ff2  = (const float*)d_in[15];
  float* outF = (float*)d_out;

  float* ws = (float*)d_ws;
  f16* qk    = (f16*)ws;
  f16* bv512 = (f16*)ws;
  f16* h1    = (f16*)ws;
  f16* h2    = (f16*)ws + 16777216;
  f16* xn    = (f16*)d_out;
  f16* o_r   = (f16*)d_out;
  f16* combT = (f16*)d_out;
  float* qprobe = ws + OFF_QPROBE;
  float* sh     = ws + OFF_SH;
  int*   ih     = (int*)(ws + OFF_IH);
  int*   iw     = (int*)(ws + OFF_IW);
  float* stm    = ws + OFF_STM;
  float* str    = ws + OFF_STR;
  float* vsel   = ws + OFF_VSEL;
  f16*   W16    = (f16*)(ws + OFF_W16);

  // 0. weights -> fp16
  hipLaunchKernelGGL(k_wcvt, dim3(896), dim3(256), 0, stream,
                     w_qkv, w_out, w_comb, w_ff1, w_ff2, W16);
  // 1. fused channel-LN -> xn fp16 (d_out)
  hipLaunchKernelGGL(k_lnxn, dim3(256), dim3(256), 0, stream, x, cln_g, cln_b, xn);
  // 2. q,k GEMM (+l2norm) -> qk fp16 (ws); 2-m-tile: gy=2 covers M=512
  hipLaunchKernelGGL(k_mf_qk2, dim3(64, 2, 8), dim3(256), 0, stream,
                     W16 + WH_QKV, xn, (size_t)CDIM * PP, qk, 256);
  // 3. probes + top-k
  hipLaunchKernelGGL(k_probe, dim3(64), dim3(256), 0, stream, qk, qprobe, sh);
  hipLaunchKernelGGL(k_topk_h, dim3(64), dim3(64), 0, stream, sh, ih);
  hipLaunchKernelGGL(k_sw_topk, dim3(64), dim3(256), 0, stream, qk, qprobe, ih, iw);
  // 4. v at selected positions (reads xn, still live)
  hipLaunchKernelGGL(k_vsel2, dim3(64), dim3(256), 0, stream, xn, W16 + WH_QKV, ih, iw, vsel);
  // 5. MFMA attention -> o_r fp16 (d_out; xn dead)
  hipLaunchKernelGGL(k_attn_mf, dim3(64, 64), dim3(256), 0, stream, qk, vsel, ih, iw, o_r);
  // 6. attn_branch GEMM -> bv512 [0,256) (qk dead); M=256 -> gy=1
  hipLaunchKernelGGL(k_mf2, dim3(64, 1, 8), dim3(256), 0, stream,
                     W16 + WH_OUT, o_r, (size_t)CDIM * PP, bv512, (size_t)512 * PP,
                     b_out, (const float*)nullptr, (size_t)0, 256);
  // 7. conv branch -> bv512 [256,512)
  hipLaunchKernelGGL(k_dw, dim3(2048, 32), dim3(256), 0, stream, x, w_dw, b_dw, bv512);
  // 8. comb GEMM (K=512, +x residual) -> combT fp16 (d_out; o_r dead); gy=1
  hipLaunchKernelGGL(k_mf2, dim3(64, 1, 8), dim3(256), 0, stream,
                     W16 + WH_COMB, bv512, (size_t)512 * PP, combT, (size_t)CDIM * PP,
                     b_comb, x, (size_t)CDIM * PP, 512);
  // 9. FF chain in batch-pairs, descending (comb-in-d_out aliasing safe)
  for (int b = 6; b >= 0; b -= 2) {
    hipLaunchKernelGGL(k_mf2, dim3(64, 4, 2), dim3(256), 0, stream,
                       W16 + WH_FF1, combT + (size_t)b * CDIM * PP, (size_t)CDIM * PP,
                       h1, (size_t)FFI * PP, b_ff1,
                       (const float*)nullptr, (size_t)0, 256);
    hipLaunchKernelGGL(k_ff_fused, dim3(FFI, 2), dim3(256), 0, stream,
                       h1, w_ffdw, b_ffdw, h2);
    hipLaunchKernelGGL(k_mf, dim3(64, 2, 2), dim3(256), 0, stream,
                       W16 + WH_FF2, h2, (size_t)FFI * PP,
                       (f16*)nullptr, outF + (size_t)b * CDIM * PP, (size_t)CDIM * PP,
                       b_ff2, (const float*)nullptr, (size_t)0, 1024);
  }
  // 10. final inorm in place on d_out
  hipLaunchKernelGGL(k_istats, dim3(2048), dim3(256), 0, stream, outF, stm, str);
  hipLaunchKernelGGL(k_napply, dim3(65536), dim3(256), 0, stream, outF, stm, str);
}

// Round 5
// 983.913 us; speedup vs baseline: 1.2418x; 1.2418x over previous
//
#include <hip/hip_runtime.h>
#include <hip/hip_fp16.h>
#include <math.h>

#define B_    8
#define CDIM  256
#define HH    256
#define WW    32
#define PP    8192
#define HEADS 8
#define FFI   1024

typedef _Float16 f16;
typedef _Float16 half8 __attribute__((ext_vector_type(8)));
typedef _Float16 half4 __attribute__((ext_vector_type(4)));
typedef _Float16 f16x2v __attribute__((ext_vector_type(2)));
typedef float f32x4 __attribute__((ext_vector_type(4)));

// ---------------- workspace layout (float offsets) ----------------
static const size_t OFF_QPROBE = 16908288;
static const size_t OFF_SH     = 16910336;
static const size_t OFF_IH     = 16912384;
static const size_t OFF_IW     = 16912896;
static const size_t OFF_STM    = 16913408;
static const size_t OFF_STR    = 16921600;
static const size_t OFF_VSEL   = 16929792;
static const size_t OFF_W16    = 17060864;   // 917504 halves = 458752 floats

// fp16 weight region offsets (in halves)
#define WH_QKV  0
#define WH_OUT  196608
#define WH_COMB 262144
#define WH_FF1  393216
#define WH_FF2  655360

// fast gelu: x*Phi(x) via A&S 7.1.26 erf, |erf err| <= 1.5e-7, branchless.
__device__ __forceinline__ float gelu_f(float x) {
  float z = fabsf(x) * 0.70710678118f;
  float t = __builtin_amdgcn_rcpf(1.0f + 0.3275911f * z);
  float poly = t * (0.254829592f +
               t * (-0.284496736f +
               t * (1.421413741f +
               t * (-1.453152027f +
               t * 1.061405429f))));
  float e = 1.0f - poly * __expf(-z * z);
  return 0.5f * x * (1.0f + copysignf(e, x));
}

// ---------------- weights -> fp16 ----------------
__global__ __launch_bounds__(256) void k_wcvt(const float* __restrict__ s0,
                                              const float* __restrict__ s1,
                                              const float* __restrict__ s2,
                                              const float* __restrict__ s3,
                                              const float* __restrict__ s4,
                                              f16* __restrict__ dst) {
  int blk = blockIdx.x;   // 896 blocks x 1024 elems
  const float* src; size_t base;
  if (blk < 192)      { src = s0; base = WH_QKV;  }
  else if (blk < 256) { src = s1; base = WH_OUT;  blk -= 192; }
  else if (blk < 384) { src = s2; base = WH_COMB; blk -= 256; }
  else if (blk < 640) { src = s3; base = WH_FF1;  blk -= 384; }
  else                { src = s4; base = WH_FF2;  blk -= 640; }
  int off = blk * 1024 + threadIdx.x * 4;
  float4 v = *(const float4*)(src + off);
  half4 h; h[0] = (f16)v.x; h[1] = (f16)v.y; h[2] = (f16)v.z; h[3] = (f16)v.w;
  *(half4*)(dst + base + off) = h;
}

// ---------------- fused channel-LN -> xn fp16 ----------------
__global__ __launch_bounds__(256) void k_lnxn(const float* __restrict__ x,
                                              const float* __restrict__ g,
                                              const float* __restrict__ bb,
                                              f16* __restrict__ xn) {
  int idx = blockIdx.x * 256 + threadIdx.x;      // 65536 = b*PP + p
  int b = idx >> 13, p = idx & 8191;
  const float* xp = x + (size_t)b * CDIM * PP + p;
  float s = 0.f, s2 = 0.f;
  for (int c = 0; c < CDIM; c++) { float v = xp[(size_t)c * PP]; s += v; s2 += v * v; }
  float m = s * (1.0f / CDIM);
  float var = s2 * (1.0f / CDIM) - m * m;
  float r = rsqrtf(var + 1e-5f);
  f16* xo = xn + (size_t)b * CDIM * PP + p;
  for (int c = 0; c < CDIM; c++)
    xo[(size_t)c * PP] = (f16)((xp[(size_t)c * PP] - m) * r * g[c] + bb[c]);
}

// ================= MFMA fp16 GEMM, 1-m-tile 256-thread (FF2 float-out) =================
#define MF_STAGE                                                                   \
  int t = threadIdx.x;                                                             \
  int nw_ = gridDim.x * gridDim.y;                                                 \
  int hb_ = blockIdx.x + gridDim.x * blockIdx.y;                                   \
  int wk_ = (hb_ & 7) * (nw_ >> 3) + (hb_ >> 3);                                   \
  int gy_ = gridDim.y;                                                             \
  int sh_ = __ffs(gy_) - 1;                                                        \
  int p0 = (wk_ >> sh_) * 128, m0 = (wk_ & (gy_ - 1)) * 128, z = blockIdx.z;       \
  int lane = t & 63, wave = t >> 6;                                                \
  int wm = (wave >> 1) * 64, wp = (wave & 1) * 64;                                 \
  int col = lane & 15, quad = lane >> 4;                                           \
  f32x4 acc[4][4];                                                                 \
  _Pragma("unroll") for (int i = 0; i < 4; i++)                                    \
  _Pragma("unroll") for (int j = 0; j < 4; j++)                                    \
      acc[i][j] = (f32x4){0.f, 0.f, 0.f, 0.f};                                     \
  int am = t >> 1, ak = (t & 1) * 16;                                              \
  int bp = (t & 15) * 8, bk = (t >> 4) * 2;                                        \
  int erot = t & 7;                                                                \
  const f16* wr0 = W + (size_t)(m0 + am) * K + ak;                                 \
  const f16* br0 = inB + (size_t)bk * PP + p0 + bp;                                \
  half8 w0 = *(const half8*)wr0;                                                   \
  half8 w1 = *(const half8*)(wr0 + 8);                                             \
  half8 r0 = *(const half8*)br0;                                                   \
  half8 r1 = *(const half8*)(br0 + PP);                                            \
  for (int k0 = 0; k0 < K; k0 += 32) {                                             \
    *(half8*)&As[am][ak] = w0;                                                     \
    *(half8*)&As[am][ak + 8] = w1;                                                 \
    _Pragma("unroll") for (int e0 = 0; e0 < 8; e0++) {                             \
      int e = (e0 + erot) & 7;                                                     \
      f16x2v pr2; pr2[0] = r0[e]; pr2[1] = r1[e];                                  \
      *(f16x2v*)&Bs[bp + e][bk] = pr2;                                             \
    }                                                                              \
    __syncthreads();                                                               \
    int kn = (k0 + 32 < K) ? k0 + 32 : k0;                                         \
    w0 = *(const half8*)(wr0 + kn);                                                \
    w1 = *(const half8*)(wr0 + kn + 8);                                            \
    r0 = *(const half8*)(inB + (size_t)(kn + bk) * PP + p0 + bp);                  \
    r1 = *(const half8*)(inB + (size_t)(kn + bk + 1) * PP + p0 + bp);              \
    half8 af[4], bf[4];                                                            \
    _Pragma("unroll") for (int i = 0; i < 4; i++)                                  \
      af[i] = *(const half8*)&As[wm + i * 16 + col][quad * 8];                     \
    _Pragma("unroll") for (int j = 0; j < 4; j++)                                  \
      bf[j] = *(const half8*)&Bs[wp + j * 16 + col][quad * 8];                     \
    _Pragma("unroll") for (int i = 0; i < 4; i++)                                  \
    _Pragma("unroll") for (int j = 0; j < 4; j++)                                  \
        acc[i][j] = __builtin_amdgcn_mfma_f32_16x16x32_f16(af[i], bf[j],           \
                                                           acc[i][j], 0, 0, 0);    \
    __syncthreads();                                                               \
  }

__global__ __launch_bounds__(256) void k_mf(const f16* __restrict__ W,
                                            const f16* __restrict__ In, size_t inZ,
                                            f16* __restrict__ OutH,
                                            float* __restrict__ OutF, size_t outZ,
                                            const float* __restrict__ bias,
                                            const float* __restrict__ resid, size_t residZ,
                                            int K) {
  __shared__ f16 As[128][40];
  __shared__ f16 Bs[128][40];
  const f16* inB = In + (size_t)blockIdx.z * inZ;
  MF_STAGE
#pragma unroll
  for (int i = 0; i < 4; i++) {
    int mb = m0 + wm + i * 16 + quad * 4;
#pragma unroll
    for (int r = 0; r < 4; r++) {
      int m = mb + r;
      float bs = bias ? bias[m] : 0.f;
#pragma unroll
      for (int j = 0; j < 4; j++) {
        int p = p0 + wp + j * 16 + col;
        float v = acc[i][j][r] + bs;
        size_t off = (size_t)z * outZ + (size_t)m * PP + p;
        if (resid) v += resid[(size_t)z * residZ + (size_t)m * PP + p];
        if (OutF) OutF[off] = v;
        else OutH[off] = (f16)v;
      }
    }
  }
}

// ========== 8-wave MFMA GEMM: 256m x 128p per block, 512 threads ==========
// Second m-tile distributed across waves (4m x 2p wave grid) -> acc stays
// [4][4] (64 VGPR), occupancy stays 4 waves/SIMD, In-panel traffic halves.
#define MF_STAGE8                                                                  \
  int t = threadIdx.x;                                                             \
  int nw_ = gridDim.x * gridDim.y;                                                 \
  int hb_ = blockIdx.x + gridDim.x * blockIdx.y;                                   \
  int wk_ = (hb_ & 7) * (nw_ >> 3) + (hb_ >> 3);                                   \
  int gy_ = gridDim.y;                                                             \
  int sh_ = __ffs(gy_) - 1;                                                        \
  int p0 = (wk_ >> sh_) * 128, m0 = (wk_ & (gy_ - 1)) * 256, z = blockIdx.z;       \
  int lane = t & 63, wave = t >> 6;                                                \
  int wm = (wave >> 1) * 64, wp = (wave & 1) * 64;                                 \
  int col = lane & 15, quad = lane >> 4;                                           \
  f32x4 acc[4][4];                                                                 \
  _Pragma("unroll") for (int i = 0; i < 4; i++)                                    \
  _Pragma("unroll") for (int j = 0; j < 4; j++)                                    \
      acc[i][j] = (f32x4){0.f, 0.f, 0.f, 0.f};                                     \
  int am = t >> 1, ak = (t & 1) * 16;                                              \
  int bp = (t & 15) * 8, bk = (t >> 4) * 2;   /* B-staging valid for t<256 */      \
  int erot = t & 7;                                                                \
  const f16* wr0 = W + (size_t)(m0 + am) * K + ak;                                 \
  const f16* br0 = inB + (size_t)(bk & 31) * PP + p0 + bp;                         \
  half8 w0 = *(const half8*)wr0;                                                   \
  half8 w1 = *(const half8*)(wr0 + 8);                                             \
  half8 r0 = {}, r1 = {};                                                          \
  if (t < 256) { r0 = *(const half8*)br0; r1 = *(const half8*)(br0 + PP); }        \
  for (int k0 = 0; k0 < K; k0 += 32) {                                             \
    *(half8*)&As[am][ak] = w0;                                                     \
    *(half8*)&As[am][ak + 8] = w1;                                                 \
    if (t < 256) {                                                                 \
      _Pragma("unroll") for (int e0 = 0; e0 < 8; e0++) {                           \
        int e = (e0 + erot) & 7;                                                   \
        f16x2v pr2; pr2[0] = r0[e]; pr2[1] = r1[e];                                \
        *(f16x2v*)&Bs[bp + e][bk] = pr2;                                           \
      }                                                                            \
    }                                                                              \
    __syncthreads();                                                               \
    int kn = (k0 + 32 < K) ? k0 + 32 : k0;                                         \
    w0 = *(const half8*)(wr0 + kn);                                                \
    w1 = *(const half8*)(wr0 + kn + 8);                                            \
    if (t < 256) {                                                                 \
      r0 = *(const half8*)(inB + (size_t)(kn + bk) * PP + p0 + bp);                \
      r1 = *(const half8*)(inB + (size_t)(kn + bk + 1) * PP + p0 + bp);            \
    }                                                                              \
    half8 af[4], bf[4];                                                            \
    _Pragma("unroll") for (int i = 0; i < 4; i++)                                  \
      af[i] = *(const half8*)&As[wm + i * 16 + col][quad * 8];                     \
    _Pragma("unroll") for (int j = 0; j < 4; j++)                                  \
      bf[j] = *(const half8*)&Bs[wp + j * 16 + col][quad * 8];                     \
    _Pragma("unroll") for (int i = 0; i < 4; i++)                                  \
    _Pragma("unroll") for (int j = 0; j < 4; j++)                                  \
        acc[i][j] = __builtin_amdgcn_mfma_f32_16x16x32_f16(af[i], bf[j],           \
                                                           acc[i][j], 0, 0, 0);    \
    __syncthreads();                                                               \
  }

__global__ __launch_bounds__(512) void k_mf8(const f16* __restrict__ W,
                                             const f16* __restrict__ In, size_t inZ,
                                             f16* __restrict__ OutH, size_t outZ,
                                             const float* __restrict__ bias,
                                             const float* __restrict__ resid, size_t residZ,
                                             int K) {
  __shared__ f16 As[256][40];
  __shared__ f16 Bs[128][40];
  const f16* inB = In + (size_t)blockIdx.z * inZ;
  MF_STAGE8
#pragma unroll
  for (int i = 0; i < 4; i++) {
    int mb = m0 + wm * 4 / 4 + i * 16 + quad * 4;   // wm spans 0..192 across 8 waves
#pragma unroll
    for (int r = 0; r < 4; r++) {
      int m = mb + r;
      float bs = bias ? bias[m] : 0.f;
#pragma unroll
      for (int j = 0; j < 4; j++) {
        int p = p0 + wp + j * 16 + col;
        float v = acc[i][j][r] + bs;
        size_t off = (size_t)z * outZ + (size_t)m * PP + p;
        if (resid) v += resid[(size_t)z * residZ + (size_t)m * PP + p];
        OutH[off] = (f16)v;
      }
    }
  }
}

// qk GEMM (8-wave): epilogue l2-normalizes groups of 32 consecutive p, stores fp16
__global__ __launch_bounds__(512) void k_mf_qk8(const f16* __restrict__ W,
                                                const f16* __restrict__ In, size_t inZ,
                                                f16* __restrict__ qkO, int K) {
  __shared__ f16 As[256][40];
  __shared__ f16 Bs[128][40];
  const f16* inB = In + (size_t)blockIdx.z * inZ;
  MF_STAGE8
#pragma unroll
  for (int i = 0; i < 4; i++) {
    int mb = m0 + wm + i * 16 + quad * 4;
#pragma unroll
    for (int r = 0; r < 4; r++) {
      int m = mb + r;
      size_t base = (size_t)z * 512 * PP + (size_t)m * PP;
#pragma unroll
      for (int jp = 0; jp < 2; jp++) {
        float a0 = acc[i][2 * jp][r], a1 = acc[i][2 * jp + 1][r];
        float ss = a0 * a0 + a1 * a1;
        ss += __shfl_xor(ss, 1);
        ss += __shfl_xor(ss, 2);
        ss += __shfl_xor(ss, 4);
        ss += __shfl_xor(ss, 8);
        float inv = 1.0f / fmaxf(sqrtf(ss), 1e-12f);
        int pa = p0 + wp + 2 * jp * 16 + col;
        qkO[base + pa] = (f16)(a0 * inv);
        qkO[base + pa + 16] = (f16)(a1 * inv);
      }
    }
  }
}

// ---------------- q_probe + sh scores (vectorized) ----------------
__global__ __launch_bounds__(256) void k_probe(const f16* __restrict__ qk,
                                               float* __restrict__ qprobe,
                                               float* __restrict__ sh) {
  __shared__ float red[64][32];
  __shared__ float qp[32];
  __shared__ float ksum[32][32];
  int bh = blockIdx.x, b = bh >> 3, hd = bh & 7;
  int t = threadIdx.x;
  const f16* qb = qk + ((size_t)(b * 512 + hd * 32)) * PP;
  {
    int g = t >> 2, wq = (t & 3) * 8;
    float s[8];
#pragma unroll
    for (int e = 0; e < 8; e++) s[e] = 0.f;
    for (int it = 0; it < 128; it++) {
      int row = g * 128 + it;
      half8 v = *(const half8*)(qb + (size_t)(row >> 8) * PP + (row & 255) * 32 + wq);
#pragma unroll
      for (int e = 0; e < 8; e++) s[e] += (float)v[e];
    }
#pragma unroll
    for (int e = 0; e < 8; e++) red[g][wq + e] = s[e];
  }
  __syncthreads();
  if (t < 32) {
    float a = 0.f;
    for (int g = 0; g < 64; g++) a += red[g][t];
    qp[t] = a;
    qprobe[bh * 32 + t] = a;
  }
  const f16* kb = qk + ((size_t)(b * 512 + 256 + hd * 32)) * PP;
  {
    int d = t >> 3, wq = (t & 7) * 4;
    float s[4] = {0.f, 0.f, 0.f, 0.f};
    for (int h = 0; h < 256; h++) {
      half4 v = *(const half4*)(kb + (size_t)d * PP + h * 32 + wq);
#pragma unroll
      for (int e = 0; e < 4; e++) s[e] += (float)v[e];
    }
#pragma unroll
    for (int e = 0; e < 4; e++) ksum[d][wq + e] = s[e];
  }
  __syncthreads();
  if (t < 32) {
    float a = 0.f;
    for (int w = 0; w < 32; w++) a += qp[w] * ksum[t][w];
    sh[bh * 32 + t] = a;
  }
}

__global__ __launch_bounds__(64) void k_topk_h(const float* __restrict__ sh, int* __restrict__ ih) {
  int bh = blockIdx.x;
  if (threadIdx.x != 0) return;
  float v[32];
#pragma unroll
  for (int i = 0; i < 32; i++) v[i] = sh[bh * 32 + i];
  for (int s = 0; s < 8; s++) {
    int bi = 0; float bv = v[0];
#pragma unroll
    for (int i = 1; i < 32; i++) { if (v[i] > bv) { bv = v[i]; bi = i; } }
    ih[bh * 8 + s] = bi;
    v[bi] = -3.4e38f;
  }
}

__global__ __launch_bounds__(256) void k_sw_topk(const f16* __restrict__ qk,
                                                 const float* __restrict__ qprobe,
                                                 const int* __restrict__ ih,
                                                 int* __restrict__ iw) {
  __shared__ float qp[32];
  __shared__ float sw[256];
  __shared__ int ihs[8];
  int bh = blockIdx.x, b = bh >> 3, hd = bh & 7;
  int t = threadIdx.x;
  if (t < 32) qp[t] = qprobe[bh * 32 + t];
  if (t < 8) ihs[t] = ih[bh * 8 + t];
  __syncthreads();
  const f16* kb = qk + ((size_t)(b * 512 + 256 + hd * 32)) * PP;
  float s = 0.f;
  for (int a = 0; a < 8; a++) {
    const f16* kd = kb + (size_t)ihs[a] * PP + t * 32;
#pragma unroll
    for (int w = 0; w < 32; w++) s += qp[w] * (float)kd[w];
  }
  sw[t] = s;
  __syncthreads();
  if (t == 0) {
    for (int sel = 0; sel < 8; sel++) {
      int bi = 0; float bv = sw[0];
      for (int i = 1; i < 256; i++) { if (sw[i] > bv) { bv = sw[i]; bi = i; } }
      iw[bh * 8 + sel] = bi;
      sw[bi] = -3.4e38f;
    }
  }
}

// ---------------- v at selected positions, LDS-staged from xn fp16 ----------------
__global__ __launch_bounds__(256) void k_vsel2(const f16* __restrict__ xn,
                                               const f16* __restrict__ W16,
                                               const int* __restrict__ ih,
                                               const int* __restrict__ iw,
                                               float* __restrict__ vsel) {
  __shared__ f16 xg[64][264];
  __shared__ float wrow[8][64];
  __shared__ int ihs[8], iws8[8];
  int bh = blockIdx.x, b = bh >> 3, hd = bh & 7;
  int t = threadIdx.x;
  if (t < 8) { ihs[t] = ih[bh * 8 + t]; iws8[t] = iw[bh * 8 + t]; }
  __syncthreads();
  float acc[8];
#pragma unroll
  for (int a = 0; a < 8; a++) acc[a] = 0.f;
  for (int c0 = 0; c0 < 256; c0 += 64) {
    for (int rep = 0; rep < 2; rep++) {
      int cc = rep * 32 + (t >> 3);
      int seg = t & 7;
#pragma unroll
      for (int u = 0; u < 4; u++) {
        int h8 = seg * 4 + u;                 // 0..31
        int bi = h8 >> 2, wq = (h8 & 3) * 8;
        half8 v = *(const half8*)(xn + ((size_t)(b * 256 + c0 + cc)) * PP + iws8[bi] * 32 + wq);
        *(half8*)&xg[cc][h8 * 8] = v;
      }
    }
    for (int rep = 0; rep < 2; rep++) {
      int idx = t + rep * 256;
      int a = idx >> 6, cc = idx & 63;
      wrow[a][cc] = (float)W16[(size_t)(512 + hd * 32 + ihs[a]) * 256 + c0 + cc];
    }
    __syncthreads();
    for (int cc = 0; cc < 64; cc++) {
      float xv = (float)xg[cc][t];
#pragma unroll
      for (int a = 0; a < 8; a++) acc[a] += wrow[a][cc] * xv;
    }
    __syncthreads();
  }
  int bi = t >> 5, w = t & 31;
#pragma unroll
  for (int a = 0; a < 8; a++)
    vsel[((size_t)bh * 64 + a * 8 + bi) * 32 + w] = acc[a];
}

// ---------------- MFMA attention ----------------
__global__ __launch_bounds__(256) void k_attn_mf(const f16* __restrict__ qk,
                                                 const float* __restrict__ vsel,
                                                 const int* __restrict__ ih,
                                                 const int* __restrict__ iw,
                                                 f16* __restrict__ o_r) {
  __shared__ f16 Ks[64][40];
  __shared__ f16 Vt[32][72];
  __shared__ f16 Ps[4][32][72];
  __shared__ f16 Os[32][136];
  __shared__ int ihs[8], iws8[8];
  int bh = blockIdx.y, b = bh >> 3, hd = bh & 7;
  int t = threadIdx.x;
  if (t < 8) { ihs[t] = ih[bh * 8 + t]; iws8[t] = iw[bh * 8 + t]; }
  __syncthreads();
  {
    int j = t >> 2, wc = (t & 3) * 8;
    const f16* kb = qk + ((size_t)(b * 512 + 256 + hd * 32 + ihs[j >> 3])) * PP
                    + iws8[j & 7] * 32 + wc;
    *(half8*)&Ks[j][wc] = *(const half8*)kb;
  }
  for (int rep = 0; rep < 2; rep++) {
    int idx = t + rep * 256;
    int j = idx >> 3, w4 = (idx & 7) * 4;
    float4 v = *(const float4*)(vsel + ((size_t)bh * 64 + j) * 32 + w4);
    Vt[w4 + 0][j] = (f16)v.x; Vt[w4 + 1][j] = (f16)v.y;
    Vt[w4 + 2][j] = (f16)v.z; Vt[w4 + 3][j] = (f16)v.w;
  }
  __syncthreads();
  int wv = t >> 6, lane = t & 63, col = lane & 15, quad = lane >> 4;
  int i0 = blockIdx.x * 128;
  int dq = i0 >> 8;
  int hb = (i0 & 255) + wv * 32;
  const f16* qbase = qk + ((size_t)(b * 512 + hd * 32 + dq)) * PP;
  f32x4 sacc[2][4];
#pragma unroll
  for (int i = 0; i < 2; i++)
#pragma unroll
    for (int j = 0; j < 4; j++) sacc[i][j] = (f32x4){0.f, 0.f, 0.f, 0.f};
#pragma unroll
  for (int mt = 0; mt < 2; mt++) {
    half8 af = *(const half8*)(qbase + (size_t)(hb + mt * 16 + col) * 32 + quad * 8);
#pragma unroll
    for (int nt = 0; nt < 4; nt++) {
      half8 bf = *(const half8*)&Ks[nt * 16 + col][quad * 8];
      sacc[mt][nt] = __builtin_amdgcn_mfma_f32_16x16x32_f16(af, bf, sacc[mt][nt], 0, 0, 0);
    }
  }
#pragma unroll
  for (int mt = 0; mt < 2; mt++) {
#pragma unroll
    for (int r = 0; r < 4; r++) {
      float s0 = sacc[mt][0][r], s1 = sacc[mt][1][r], s2 = sacc[mt][2][r], s3 = sacc[mt][3][r];
      float mx = fmaxf(fmaxf(s0, s1), fmaxf(s2, s3));
      mx = fmaxf(mx, __shfl_xor(mx, 1));
      mx = fmaxf(mx, __shfl_xor(mx, 2));
      mx = fmaxf(mx, __shfl_xor(mx, 4));
      mx = fmaxf(mx, __shfl_xor(mx, 8));
      float e0 = __expf(s0 - mx), e1 = __expf(s1 - mx), e2 = __expf(s2 - mx), e3 = __expf(s3 - mx);
      float l = e0 + e1 + e2 + e3;
      l += __shfl_xor(l, 1);
      l += __shfl_xor(l, 2);
      l += __shfl_xor(l, 4);
      l += __shfl_xor(l, 8);
      float inv = 1.0f / l;
      int row = mt * 16 + quad * 4 + r;
      Ps[wv][row][0 * 16 + col] = (f16)(e0 * inv);
      Ps[wv][row][1 * 16 + col] = (f16)(e1 * inv);
      Ps[wv][row][2 * 16 + col] = (f16)(e2 * inv);
      Ps[wv][row][3 * 16 + col] = (f16)(e3 * inv);
    }
  }
  __syncthreads();
  f32x4 oacc[2][2];
#pragma unroll
  for (int i = 0; i < 2; i++)
#pragma unroll
    for (int j = 0; j < 2; j++) oacc[i][j] = (f32x4){0.f, 0.f, 0.f, 0.f};
#pragma unroll
  for (int kk = 0; kk < 2; kk++) {
    half8 ap[2], bv[2];
#pragma unroll
    for (int mt = 0; mt < 2; mt++) ap[mt] = *(const half8*)&Ps[wv][mt * 16 + col][kk * 32 + quad * 8];
#pragma unroll
    for (int wn = 0; wn < 2; wn++) bv[wn] = *(const half8*)&Vt[wn * 16 + col][kk * 32 + quad * 8];
#pragma unroll
    for (int mt = 0; mt < 2; mt++)
#pragma unroll
      for (int wn = 0; wn < 2; wn++)
        oacc[mt][wn] = __builtin_amdgcn_mfma_f32_16x16x32_f16(ap[mt], bv[wn], oacc[mt][wn], 0, 0, 0);
  }
#pragma unroll
  for (int mt = 0; mt < 2; mt++)
#pragma unroll
    for (int wn = 0; wn < 2; wn++)
#pragma unroll
      for (int r = 0; r < 4; r++)
        Os[wn * 16 + col][wv * 32 + mt * 16 + quad * 4 + r] = (f16)oacc[mt][wn][r];
  __syncthreads();
  {
    int dd = t >> 3, seg = t & 7;
#pragma unroll
    for (int u = 0; u < 2; u++) {
      int io = (seg * 2 + u) * 8;
      *(half8*)(o_r + ((size_t)(b * 256 + hd * 32 + dd)) * PP + i0 + io) = *(const half8*)&Os[dd][io];
    }
  }
}

// ---------------- conv branch dw3x3 on x -> fp16 channels [256,512) of bv512 ----------------
__global__ __launch_bounds__(256) void k_dw(const float* __restrict__ in,
                                            const float* __restrict__ wdw,
                                            const float* __restrict__ bdw,
                                            f16* __restrict__ out) {
  int bc = blockIdx.x;
  int b = bc >> 8, c = bc & 255;
  int p = blockIdx.y * 256 + threadIdx.x;
  int x0 = p >> 5, y0 = p & 31;
  const float* ip = in + (size_t)bc * PP;
  const float* wp = wdw + c * 9;
  float s = bdw[c];
#pragma unroll
  for (int i = 0; i < 3; i++) {
    int xx = x0 + i - 1;
    if (xx < 0 || xx >= HH) continue;
#pragma unroll
    for (int j = 0; j < 3; j++) {
      int yy = y0 + j - 1;
      if (yy < 0 || yy >= WW) continue;
      s += wp[i * 3 + j] * ip[xx * 32 + yy];
    }
  }
  out[((size_t)(b * 512 + 256 + c)) * PP + p] = (f16)s;
}

// ======== fused FF inner: gelu(inorm(h1)) -> dwconv -> gelu(inorm(.)) + residual ========
__global__ __launch_bounds__(256) void k_ff_fused(const f16* __restrict__ h1,
                                                  const float* __restrict__ wdw,
                                                  const float* __restrict__ bdw,
                                                  f16* __restrict__ h2) {
  __shared__ float gbuf[256 * 33];
  __shared__ float redA[8], redB[8];
  int c = blockIdx.x, zz = blockIdx.y;
  int t = threadIdx.x;
  int wv = t >> 6, lane = t & 63;
  const f16* hp = h1 + ((size_t)zz * FFI + c) * PP;
  f16* out = h2 + ((size_t)zz * FFI + c) * PP;

  float v[32];
  float s = 0.f, s2 = 0.f;
#pragma unroll
  for (int u = 0; u < 4; u++) {
    half8 h = *(const half8*)(hp + (u * 256 + t) * 8);
#pragma unroll
    for (int e = 0; e < 8; e++) { float f = (float)h[e]; v[u * 8 + e] = f; s += f; s2 += f * f; }
  }
#pragma unroll
  for (int o = 32; o; o >>= 1) { s += __shfl_xor(s, o); s2 += __shfl_xor(s2, o); }
  if (lane == 0) { redA[wv] = s; redA[4 + wv] = s2; }
  __syncthreads();
  float m = (redA[0] + redA[1] + redA[2] + redA[3]) * (1.0f / PP);
  float s2a = (redA[4] + redA[5] + redA[6] + redA[7]) * (1.0f / PP);
  float r = rsqrtf(s2a - m * m + 1e-5f);

#pragma unroll
  for (int u = 0; u < 4; u++) {
    int base = (u * 256 + t) * 8;
    int row = base >> 5, colb = base & 31;
#pragma unroll
    for (int e = 0; e < 8; e++)
      gbuf[row * 33 + colb + e] = gelu_f((v[u * 8 + e] - m) * r);
  }
  __syncthreads();

  float wf[9];
#pragma unroll
  for (int i = 0; i < 9; i++) wf[i] = wdw[c * 9 + i];
  float bd = bdw[c];
  float g0[32];
#pragma unroll
  for (int y = 0; y < 32; y++) g0[y] = gbuf[t * 33 + y];
  const float* up = (t > 0) ? &gbuf[(t - 1) * 33] : nullptr;
  const float* dn = (t < 255) ? &gbuf[(t + 1) * 33] : nullptr;
  float d[32];
  float sd = 0.f, sd2 = 0.f;
#pragma unroll
  for (int y = 0; y < 32; y++) {
    float um1 = 0.f, u0 = 0.f, up1 = 0.f;
    float dm1 = 0.f, d0 = 0.f, dp1 = 0.f;
    if (up) { u0 = up[y]; if (y > 0) um1 = up[y - 1]; if (y < 31) up1 = up[y + 1]; }
    if (dn) { d0 = dn[y]; if (y > 0) dm1 = dn[y - 1]; if (y < 31) dp1 = dn[y + 1]; }
    float a = bd + wf[1] * u0 + wf[4] * g0[y] + wf[7] * d0;
    if (y > 0)  a += wf[0] * um1 + wf[3] * g0[y - 1] + wf[6] * dm1;
    if (y < 31) a += wf[2] * up1 + wf[5] * g0[y + 1] + wf[8] * dp1;
    d[y] = a; sd += a; sd2 += a * a;
  }
#pragma unroll
  for (int o = 32; o; o >>= 1) { sd += __shfl_xor(sd, o); sd2 += __shfl_xor(sd2, o); }
  if (lane == 0) { redB[wv] = sd; redB[4 + wv] = sd2; }
  __syncthreads();
  float dm = (redB[0] + redB[1] + redB[2] + redB[3]) * (1.0f / PP);
  float dv = (redB[4] + redB[5] + redB[6] + redB[7]) * (1.0f / PP);
  float dr = rsqrtf(dv - dm * dm + 1e-5f);

#pragma unroll
  for (int y = 0; y < 32; y++)
    gbuf[t * 33 + y] = g0[y] + gelu_f((d[y] - dm) * dr);
  __syncthreads();

#pragma unroll
  for (int u = 0; u < 4; u++) {
    int base = (u * 256 + t) * 8;
    int row = base >> 5, colb = base & 31;
    half8 h;
#pragma unroll
    for (int e = 0; e < 8; e++) h[e] = (f16)gbuf[row * 33 + colb + e];
    *(half8*)(out + base) = h;
  }
}

// ---------------- fp32 inorm stats + apply (final) ----------------
__global__ __launch_bounds__(256) void k_istats(const float* __restrict__ in,
                                                float* __restrict__ stm,
                                                float* __restrict__ str) {
  __shared__ float ss[256], ss2[256];
  int row = blockIdx.x, t = threadIdx.x;
  const float* p = in + (size_t)row * PP;
  float s = 0.f, s2 = 0.f;
  for (int i = t; i < PP; i += 256) { float v = p[i]; s += v; s2 += v * v; }
  ss[t] = s; ss2[t] = s2;
  __syncthreads();
  for (int off = 128; off; off >>= 1) {
    if (t < off) { ss[t] += ss[t + off]; ss2[t] += ss2[t + off]; }
    __syncthreads();
  }
  if (t == 0) {
    float m = ss[0] * (1.0f / PP);
    float var = ss2[0] * (1.0f / PP) - m * m;
    stm[row] = m;
    str[row] = rsqrtf(var + 1e-5f);
  }
}

__global__ __launch_bounds__(256) void k_napply(float* __restrict__ io,
                                                const float* __restrict__ stm,
                                                const float* __restrict__ str) {
  size_t idx = (size_t)blockIdx.x * 256 + threadIdx.x;
  int row = (int)(idx >> 13);
  io[idx] = (io[idx] - stm[row]) * str[row];
}

extern "C" void kernel_launch(void* const* d_in, const int* in_sizes, int n_in,
                              void* d_out, int out_size, void* d_ws, size_t ws_size,
                              hipStream_t stream) {
  const float* x      = (const float*)d_in[0];
  const float* cln_g  = (const float*)d_in[1];
  const float* cln_b  = (const float*)d_in[2];
  const float* w_qkv  = (const float*)d_in[3];
  const float* w_out  = (const float*)d_in[4];
  const float* b_out  = (const float*)d_in[5];
  const float* w_dw   = (const float*)d_in[6];
  const float* b_dw   = (const float*)d_in[7];
  const float* w_comb = (const float*)d_in[8];
  const float* b_comb = (const float*)d_in[9];
  const float* w_ff1  = (const float*)d_in[10];
  const float* b_ff1  = (const float*)d_in[11];
  const float* w_ffdw = (const float*)d_in[12];
  const float* b_ffdw = (const float*)d_in[13];
  const float* w_ff2  = (const float*)d_in[14];
  const float* b_ff2  = (const float*)d_in[15];
  float* outF = (float*)d_out;

  float* ws = (float*)d_ws;
  f16* qk    = (f16*)ws;
  f16* bv512 = (f16*)ws;
  f16* h1    = (f16*)ws;
  f16* h2    = (f16*)ws + 16777216;
  f16* xn    = (f16*)d_out;
  f16* o_r   = (f16*)d_out;
  f16* combT = (f16*)d_out;
  float* qprobe = ws + OFF_QPROBE;
  float* sh     = ws + OFF_SH;
  int*   ih     = (int*)(ws + OFF_IH);
  int*   iw     = (int*)(ws + OFF_IW);
  float* stm    = ws + OFF_STM;
  float* str    = ws + OFF_STR;
  float* vsel   = ws + OFF_VSEL;
  f16*   W16    = (f16*)(ws + OFF_W16);

  // 0. weights -> fp16
  hipLaunchKernelGGL(k_wcvt, dim3(896), dim3(256), 0, stream,
                     w_qkv, w_out, w_comb, w_ff1, w_ff2, W16);
  // 1. fused channel-LN -> xn fp16 (d_out)
  hipLaunchKernelGGL(k_lnxn, dim3(256), dim3(256), 0, stream, x, cln_g, cln_b, xn);
  // 2. q,k GEMM (+l2norm) -> qk fp16 (ws); 8-wave 256m-tile, gy=2 covers M=512
  hipLaunchKernelGGL(k_mf_qk8, dim3(64, 2, 8), dim3(512), 0, stream,
                     W16 + WH_QKV, xn, (size_t)CDIM * PP, qk, 256);
  // 3. probes + top-k
  hipLaunchKernelGGL(k_probe, dim3(64), dim3(256), 0, stream, qk, qprobe, sh);
  hipLaunchKernelGGL(k_topk_h, dim3(64), dim3(64), 0, stream, sh, ih);
  hipLaunchKernelGGL(k_sw_topk, dim3(64), dim3(256), 0, stream, qk, qprobe, ih, iw);
  // 4. v at selected positions (reads xn, still live)
  hipLaunchKernelGGL(k_vsel2, dim3(64), dim3(256), 0, stream, xn, W16 + WH_QKV, ih, iw, vsel);
  // 5. MFMA attention -> o_r fp16 (d_out; xn dead)
  hipLaunchKernelGGL(k_attn_mf, dim3(64, 64), dim3(256), 0, stream, qk, vsel, ih, iw, o_r);
  // 6. attn_branch GEMM -> bv512 [0,256) (qk dead); M=256 -> gy=1
  hipLaunchKernelGGL(k_mf8, dim3(64, 1, 8), dim3(512), 0, stream,
                     W16 + WH_OUT, o_r, (size_t)CDIM * PP, bv512, (size_t)512 * PP,
                     b_out, (const float*)nullptr, (size_t)0, 256);
  // 7. conv branch -> bv512 [256,512)
  hipLaunchKernelGGL(k_dw, dim3(2048, 32), dim3(256), 0, stream, x, w_dw, b_dw, bv512);
  // 8. comb GEMM (K=512, +x residual) -> combT fp16 (d_out; o_r dead); gy=1
  hipLaunchKernelGGL(k_mf8, dim3(64, 1, 8), dim3(512), 0, stream,
                     W16 + WH_COMB, bv512, (size_t)512 * PP, combT, (size_t)CDIM * PP,
                     b_comb, x, (size_t)CDIM * PP, 512);
  // 9. FF chain in batch-pairs, descending (comb-in-d_out aliasing safe)
  for (int b = 6; b >= 0; b -= 2) {
    hipLaunchKernelGGL(k_mf8, dim3(64, 4, 2), dim3(512), 0, stream,
                       W16 + WH_FF1, combT + (size_t)b * CDIM * PP, (size_t)CDIM * PP,
                       h1, (size_t)FFI * PP, b_ff1,
                       (const float*)nullptr, (size_t)0, 256);
    hipLaunchKernelGGL(k_ff_fused, dim3(FFI, 2), dim3(256), 0, stream,
                       h1, w_ffdw, b_ffdw, h2);
    hipLaunchKernelGGL(k_mf, dim3(64, 2, 2), dim3(256), 0, stream,
                       W16 + WH_FF2, h2, (size_t)FFI * PP,
                       (f16*)nullptr, outF + (size_t)b * CDIM * PP, (size_t)CDIM * PP,
                       b_ff2, (const float*)nullptr, (size_t)0, 1024);
  }
  // 10. final inorm in place on d_out
  hipLaunchKernelGGL(k_istats, dim3(2048), dim3(256), 0, stream, outF, stm, str);
  hipLaunchKernelGGL(k_napply, dim3(65536), dim3(256), 0, stream, outF, stm, str);
}

// Round 6
// 969.384 us; speedup vs baseline: 1.2604x; 1.0150x over previous
//
#include <hip/hip_runtime.h>
#include <hip/hip_fp16.h>
#include <math.h>

#define B_    8
#define CDIM  256
#define HH    256
#define WW    32
#define PP    8192
#define HEADS 8
#define FFI   1024

typedef _Float16 f16;
typedef _Float16 half8 __attribute__((ext_vector_type(8)));
typedef _Float16 half4 __attribute__((ext_vector_type(4)));
typedef _Float16 f16x2v __attribute__((ext_vector_type(2)));
typedef float f32x4 __attribute__((ext_vector_type(4)));

// soft barrier: LDS-only fence. Drains ds ops (lgkmcnt) but lets register-
// destined global prefetch loads stay in flight across the barrier; the
// compiler inserts its own counted vmcnt(N) before the ds_write that uses them.
#define SOFT_BARRIER() asm volatile("s_waitcnt lgkmcnt(0)\n\ts_barrier" ::: "memory")

// ---------------- workspace layout (float offsets) ----------------
static const size_t OFF_QPROBE = 16908288;
static const size_t OFF_SH     = 16910336;
static const size_t OFF_IH     = 16912384;
static const size_t OFF_IW     = 16912896;
static const size_t OFF_STM    = 16913408;
static const size_t OFF_STR    = 16921600;
static const size_t OFF_VSEL   = 16929792;
static const size_t OFF_W16    = 17060864;   // 917504 halves = 458752 floats

// fp16 weight region offsets (in halves)
#define WH_QKV  0
#define WH_OUT  196608
#define WH_COMB 262144
#define WH_FF1  393216
#define WH_FF2  655360

// fast gelu: x*Phi(x) via A&S 7.1.26 erf, |erf err| <= 1.5e-7, branchless.
__device__ __forceinline__ float gelu_f(float x) {
  float z = fabsf(x) * 0.70710678118f;
  float t = __builtin_amdgcn_rcpf(1.0f + 0.3275911f * z);
  float poly = t * (0.254829592f +
               t * (-0.284496736f +
               t * (1.421413741f +
               t * (-1.453152027f +
               t * 1.061405429f))));
  float e = 1.0f - poly * __expf(-z * z);
  return 0.5f * x * (1.0f + copysignf(e, x));
}

// ---------------- weights -> fp16 ----------------
__global__ __launch_bounds__(256) void k_wcvt(const float* __restrict__ s0,
                                              const float* __restrict__ s1,
                                              const float* __restrict__ s2,
                                              const float* __restrict__ s3,
                                              const float* __restrict__ s4,
                                              f16* __restrict__ dst) {
  int blk = blockIdx.x;   // 896 blocks x 1024 elems
  const float* src; size_t base;
  if (blk < 192)      { src = s0; base = WH_QKV;  }
  else if (blk < 256) { src = s1; base = WH_OUT;  blk -= 192; }
  else if (blk < 384) { src = s2; base = WH_COMB; blk -= 256; }
  else if (blk < 640) { src = s3; base = WH_FF1;  blk -= 384; }
  else                { src = s4; base = WH_FF2;  blk -= 640; }
  int off = blk * 1024 + threadIdx.x * 4;
  float4 v = *(const float4*)(src + off);
  half4 h; h[0] = (f16)v.x; h[1] = (f16)v.y; h[2] = (f16)v.z; h[3] = (f16)v.w;
  *(half4*)(dst + base + off) = h;
}

// ---------------- fused channel-LN -> xn fp16 ----------------
__global__ __launch_bounds__(256) void k_lnxn(const float* __restrict__ x,
                                              const float* __restrict__ g,
                                              const float* __restrict__ bb,
                                              f16* __restrict__ xn) {
  int idx = blockIdx.x * 256 + threadIdx.x;      // 65536 = b*PP + p
  int b = idx >> 13, p = idx & 8191;
  const float* xp = x + (size_t)b * CDIM * PP + p;
  float s = 0.f, s2 = 0.f;
  for (int c = 0; c < CDIM; c++) { float v = xp[(size_t)c * PP]; s += v; s2 += v * v; }
  float m = s * (1.0f / CDIM);
  float var = s2 * (1.0f / CDIM) - m * m;
  float r = rsqrtf(var + 1e-5f);
  f16* xo = xn + (size_t)b * CDIM * PP + p;
  for (int c = 0; c < CDIM; c++)
    xo[(size_t)c * PP] = (f16)((xp[(size_t)c * PP] - m) * r * g[c] + bb[c]);
}

// ================= MFMA fp16 GEMM, 1-m-tile 256-thread (FF2 float-out) =================
#define MF_STAGE                                                                   \
  int t = threadIdx.x;                                                             \
  int nw_ = gridDim.x * gridDim.y;                                                 \
  int hb_ = blockIdx.x + gridDim.x * blockIdx.y;                                   \
  int wk_ = (hb_ & 7) * (nw_ >> 3) + (hb_ >> 3);                                   \
  int gy_ = gridDim.y;                                                             \
  int sh_ = __ffs(gy_) - 1;                                                        \
  int p0 = (wk_ >> sh_) * 128, m0 = (wk_ & (gy_ - 1)) * 128, z = blockIdx.z;       \
  int lane = t & 63, wave = t >> 6;                                                \
  int wm = (wave >> 1) * 64, wp = (wave & 1) * 64;                                 \
  int col = lane & 15, quad = lane >> 4;                                           \
  f32x4 acc[4][4];                                                                 \
  _Pragma("unroll") for (int i = 0; i < 4; i++)                                    \
  _Pragma("unroll") for (int j = 0; j < 4; j++)                                    \
      acc[i][j] = (f32x4){0.f, 0.f, 0.f, 0.f};                                     \
  int am = t >> 1, ak = (t & 1) * 16;                                              \
  int bp = (t & 15) * 8, bk = (t >> 4) * 2;                                        \
  int erot = t & 7;                                                                \
  const f16* wr0 = W + (size_t)(m0 + am) * K + ak;                                 \
  const f16* br0 = inB + (size_t)bk * PP + p0 + bp;                                \
  half8 w0 = *(const half8*)wr0;                                                   \
  half8 w1 = *(const half8*)(wr0 + 8);                                             \
  half8 r0 = *(const half8*)br0;                                                   \
  half8 r1 = *(const half8*)(br0 + PP);                                            \
  for (int k0 = 0; k0 < K; k0 += 32) {                                             \
    *(half8*)&As[am][ak] = w0;                                                     \
    *(half8*)&As[am][ak + 8] = w1;                                                 \
    _Pragma("unroll") for (int e0 = 0; e0 < 8; e0++) {                             \
      int e = (e0 + erot) & 7;                                                     \
      f16x2v pr2; pr2[0] = r0[e]; pr2[1] = r1[e];                                  \
      *(f16x2v*)&Bs[bp + e][bk] = pr2;                                             \
    }                                                                              \
    SOFT_BARRIER();                                                                \
    int kn = (k0 + 32 < K) ? k0 + 32 : k0;                                         \
    w0 = *(const half8*)(wr0 + kn);                                                \
    w1 = *(const half8*)(wr0 + kn + 8);                                            \
    r0 = *(const half8*)(inB + (size_t)(kn + bk) * PP + p0 + bp);                  \
    r1 = *(const half8*)(inB + (size_t)(kn + bk + 1) * PP + p0 + bp);              \
    half8 af[4], bf[4];                                                            \
    _Pragma("unroll") for (int i = 0; i < 4; i++)                                  \
      af[i] = *(const half8*)&As[wm + i * 16 + col][quad * 8];                     \
    _Pragma("unroll") for (int j = 0; j < 4; j++)                                  \
      bf[j] = *(const half8*)&Bs[wp + j * 16 + col][quad * 8];                     \
    _Pragma("unroll") for (int i = 0; i < 4; i++)                                  \
    _Pragma("unroll") for (int j = 0; j < 4; j++)                                  \
        acc[i][j] = __builtin_amdgcn_mfma_f32_16x16x32_f16(af[i], bf[j],           \
                                                           acc[i][j], 0, 0, 0);    \
    SOFT_BARRIER();                                                                \
  }

__global__ __launch_bounds__(256) void k_mf(const f16* __restrict__ W,
                                            const f16* __restrict__ In, size_t inZ,
                                            f16* __restrict__ OutH,
                                            float* __restrict__ OutF, size_t outZ,
                                            const float* __restrict__ bias,
                                            const float* __restrict__ resid, size_t residZ,
                                            int K) {
  __shared__ f16 As[128][40];
  __shared__ f16 Bs[128][40];
  const f16* inB = In + (size_t)blockIdx.z * inZ;
  MF_STAGE
#pragma unroll
  for (int i = 0; i < 4; i++) {
    int mb = m0 + wm + i * 16 + quad * 4;
#pragma unroll
    for (int r = 0; r < 4; r++) {
      int m = mb + r;
      float bs = bias ? bias[m] : 0.f;
#pragma unroll
      for (int j = 0; j < 4; j++) {
        int p = p0 + wp + j * 16 + col;
        float v = acc[i][j][r] + bs;
        size_t off = (size_t)z * outZ + (size_t)m * PP + p;
        if (resid) v += resid[(size_t)z * residZ + (size_t)m * PP + p];
        if (OutF) __builtin_nontemporal_store(v, OutF + off);
        else __builtin_nontemporal_store((f16)v, OutH + off);
      }
    }
  }
}

// ========== 8-wave MFMA GEMM: 256m x 128p per block, 512 threads ==========
#define MF_STAGE8                                                                  \
  int t = threadIdx.x;                                                             \
  int nw_ = gridDim.x * gridDim.y;                                                 \
  int hb_ = blockIdx.x + gridDim.x * blockIdx.y;                                   \
  int wk_ = (hb_ & 7) * (nw_ >> 3) + (hb_ >> 3);                                   \
  int gy_ = gridDim.y;                                                             \
  int sh_ = __ffs(gy_) - 1;                                                        \
  int p0 = (wk_ >> sh_) * 128, m0 = (wk_ & (gy_ - 1)) * 256, z = blockIdx.z;       \
  int lane = t & 63, wave = t >> 6;                                                \
  int wm = (wave >> 1) * 64, wp = (wave & 1) * 64;                                 \
  int col = lane & 15, quad = lane >> 4;                                           \
  f32x4 acc[4][4];                                                                 \
  _Pragma("unroll") for (int i = 0; i < 4; i++)                                    \
  _Pragma("unroll") for (int j = 0; j < 4; j++)                                    \
      acc[i][j] = (f32x4){0.f, 0.f, 0.f, 0.f};                                     \
  int am = t >> 1, ak = (t & 1) * 16;                                              \
  int bp = (t & 15) * 8, bk = (t >> 4) * 2;   /* B-staging valid for t<256 */      \
  int erot = t & 7;                                                                \
  const f16* wr0 = W + (size_t)(m0 + am) * K + ak;                                 \
  const f16* br0 = inB + (size_t)(bk & 31) * PP + p0 + bp;                         \
  half8 w0 = *(const half8*)wr0;                                                   \
  half8 w1 = *(const half8*)(wr0 + 8);                                             \
  half8 r0 = {}, r1 = {};                                                          \
  if (t < 256) { r0 = *(const half8*)br0; r1 = *(const half8*)(br0 + PP); }        \
  for (int k0 = 0; k0 < K; k0 += 32) {                                             \
    *(half8*)&As[am][ak] = w0;                                                     \
    *(half8*)&As[am][ak + 8] = w1;                                                 \
    if (t < 256) {                                                                 \
      _Pragma("unroll") for (int e0 = 0; e0 < 8; e0++) {                           \
        int e = (e0 + erot) & 7;                                                   \
        f16x2v pr2; pr2[0] = r0[e]; pr2[1] = r1[e];                                \
        *(f16x2v*)&Bs[bp + e][bk] = pr2;                                           \
      }                                                                            \
    }                                                                              \
    SOFT_BARRIER();                                                                \
    int kn = (k0 + 32 < K) ? k0 + 32 : k0;                                         \
    w0 = *(const half8*)(wr0 + kn);                                                \
    w1 = *(const half8*)(wr0 + kn + 8);                                            \
    if (t < 256) {                                                                 \
      r0 = *(const half8*)(inB + (size_t)(kn + bk) * PP + p0 + bp);                \
      r1 = *(const half8*)(inB + (size_t)(kn + bk + 1) * PP + p0 + bp);            \
    }                                                                              \
    half8 af[4], bf[4];                                                            \
    _Pragma("unroll") for (int i = 0; i < 4; i++)                                  \
      af[i] = *(const half8*)&As[wm + i * 16 + col][quad * 8];                     \
    _Pragma("unroll") for (int j = 0; j < 4; j++)                                  \
      bf[j] = *(const half8*)&Bs[wp + j * 16 + col][quad * 8];                     \
    _Pragma("unroll") for (int i = 0; i < 4; i++)                                  \
    _Pragma("unroll") for (int j = 0; j < 4; j++)                                  \
        acc[i][j] = __builtin_amdgcn_mfma_f32_16x16x32_f16(af[i], bf[j],           \
                                                           acc[i][j], 0, 0, 0);    \
    SOFT_BARRIER();                                                                \
  }

__global__ __launch_bounds__(512) void k_mf8(const f16* __restrict__ W,
                                             const f16* __restrict__ In, size_t inZ,
                                             f16* __restrict__ OutH, size_t outZ,
                                             const float* __restrict__ bias,
                                             const float* __restrict__ resid, size_t residZ,
                                             int K) {
  __shared__ f16 As[256][40];
  __shared__ f16 Bs[128][40];
  const f16* inB = In + (size_t)blockIdx.z * inZ;
  MF_STAGE8
#pragma unroll
  for (int i = 0; i < 4; i++) {
    int mb = m0 + wm + i * 16 + quad * 4;   // wm spans 0..192 across 8 waves
#pragma unroll
    for (int r = 0; r < 4; r++) {
      int m = mb + r;
      float bs = bias ? bias[m] : 0.f;
#pragma unroll
      for (int j = 0; j < 4; j++) {
        int p = p0 + wp + j * 16 + col;
        float v = acc[i][j][r] + bs;
        size_t off = (size_t)z * outZ + (size_t)m * PP + p;
        if (resid) v += resid[(size_t)z * residZ + (size_t)m * PP + p];
        __builtin_nontemporal_store((f16)v, OutH + off);
      }
    }
  }
}

// qk GEMM (8-wave): epilogue l2-normalizes groups of 32 consecutive p, stores fp16
__global__ __launch_bounds__(512) void k_mf_qk8(const f16* __restrict__ W,
                                                const f16* __restrict__ In, size_t inZ,
                                                f16* __restrict__ qkO, int K) {
  __shared__ f16 As[256][40];
  __shared__ f16 Bs[128][40];
  const f16* inB = In + (size_t)blockIdx.z * inZ;
  MF_STAGE8
#pragma unroll
  for (int i = 0; i < 4; i++) {
    int mb = m0 + wm + i * 16 + quad * 4;
#pragma unroll
    for (int r = 0; r < 4; r++) {
      int m = mb + r;
      size_t base = (size_t)z * 512 * PP + (size_t)m * PP;
#pragma unroll
      for (int jp = 0; jp < 2; jp++) {
        float a0 = acc[i][2 * jp][r], a1 = acc[i][2 * jp + 1][r];
        float ss = a0 * a0 + a1 * a1;
        ss += __shfl_xor(ss, 1);
        ss += __shfl_xor(ss, 2);
        ss += __shfl_xor(ss, 4);
        ss += __shfl_xor(ss, 8);
        float inv = 1.0f / fmaxf(sqrtf(ss), 1e-12f);
        int pa = p0 + wp + 2 * jp * 16 + col;
        __builtin_nontemporal_store((f16)(a0 * inv), qkO + base + pa);
        __builtin_nontemporal_store((f16)(a1 * inv), qkO + base + pa + 16);
      }
    }
  }
}

// ---------------- q_probe + sh scores (vectorized) ----------------
__global__ __launch_bounds__(256) void k_probe(const f16* __restrict__ qk,
                                               float* __restrict__ qprobe,
                                               float* __restrict__ sh) {
  __shared__ float red[64][32];
  __shared__ float qp[32];
  __shared__ float ksum[32][32];
  int bh = blockIdx.x, b = bh >> 3, hd = bh & 7;
  int t = threadIdx.x;
  const f16* qb = qk + ((size_t)(b * 512 + hd * 32)) * PP;
  {
    int g = t >> 2, wq = (t & 3) * 8;
    float s[8];
#pragma unroll
    for (int e = 0; e < 8; e++) s[e] = 0.f;
    for (int it = 0; it < 128; it++) {
      int row = g * 128 + it;
      half8 v = *(const half8*)(qb + (size_t)(row >> 8) * PP + (row & 255) * 32 + wq);
#pragma unroll
      for (int e = 0; e < 8; e++) s[e] += (float)v[e];
    }
#pragma unroll
    for (int e = 0; e < 8; e++) red[g][wq + e] = s[e];
  }
  __syncthreads();
  if (t < 32) {
    float a = 0.f;
    for (int g = 0; g < 64; g++) a += red[g][t];
    qp[t] = a;
    qprobe[bh * 32 + t] = a;
  }
  const f16* kb = qk + ((size_t)(b * 512 + 256 + hd * 32)) * PP;
  {
    int d = t >> 3, wq = (t & 7) * 4;
    float s[4] = {0.f, 0.f, 0.f, 0.f};
    for (int h = 0; h < 256; h++) {
      half4 v = *(const half4*)(kb + (size_t)d * PP + h * 32 + wq);
#pragma unroll
      for (int e = 0; e < 4; e++) s[e] += (float)v[e];
    }
#pragma unroll
    for (int e = 0; e < 4; e++) ksum[d][wq + e] = s[e];
  }
  __syncthreads();
  if (t < 32) {
    float a = 0.f;
    for (int w = 0; w < 32; w++) a += qp[w] * ksum[t][w];
    sh[bh * 32 + t] = a;
  }
}

__global__ __launch_bounds__(64) void k_topk_h(const float* __restrict__ sh, int* __restrict__ ih) {
  int bh = blockIdx.x;
  if (threadIdx.x != 0) return;
  float v[32];
#pragma unroll
  for (int i = 0; i < 32; i++) v[i] = sh[bh * 32 + i];
  for (int s = 0; s < 8; s++) {
    int bi = 0; float bv = v[0];
#pragma unroll
    for (int i = 1; i < 32; i++) { if (v[i] > bv) { bv = v[i]; bi = i; } }
    ih[bh * 8 + s] = bi;
    v[bi] = -3.4e38f;
  }
}

__global__ __launch_bounds__(256) void k_sw_topk(const f16* __restrict__ qk,
                                                 const float* __restrict__ qprobe,
                                                 const int* __restrict__ ih,
                                                 int* __restrict__ iw) {
  __shared__ float qp[32];
  __shared__ float sw[256];
  __shared__ int ihs[8];
  int bh = blockIdx.x, b = bh >> 3, hd = bh & 7;
  int t = threadIdx.x;
  if (t < 32) qp[t] = qprobe[bh * 32 + t];
  if (t < 8) ihs[t] = ih[bh * 8 + t];
  __syncthreads();
  const f16* kb = qk + ((size_t)(b * 512 + 256 + hd * 32)) * PP;
  float s = 0.f;
  for (int a = 0; a < 8; a++) {
    const f16* kd = kb + (size_t)ihs[a] * PP + t * 32;
#pragma unroll
    for (int w = 0; w < 32; w++) s += qp[w] * (float)kd[w];
  }
  sw[t] = s;
  __syncthreads();
  if (t == 0) {
    for (int sel = 0; sel < 8; sel++) {
      int bi = 0; float bv = sw[0];
      for (int i = 1; i < 256; i++) { if (sw[i] > bv) { bv = sw[i]; bi = i; } }
      iw[bh * 8 + sel] = bi;
      sw[bi] = -3.4e38f;
    }
  }
}

// ---------------- v at selected positions, LDS-staged from xn fp16 ----------------
__global__ __launch_bounds__(256) void k_vsel2(const f16* __restrict__ xn,
                                               const f16* __restrict__ W16,
                                               const int* __restrict__ ih,
                                               const int* __restrict__ iw,
                                               float* __restrict__ vsel) {
  __shared__ f16 xg[64][264];
  __shared__ float wrow[8][64];
  __shared__ int ihs[8], iws8[8];
  int bh = blockIdx.x, b = bh >> 3, hd = bh & 7;
  int t = threadIdx.x;
  if (t < 8) { ihs[t] = ih[bh * 8 + t]; iws8[t] = iw[bh * 8 + t]; }
  __syncthreads();
  float acc[8];
#pragma unroll
  for (int a = 0; a < 8; a++) acc[a] = 0.f;
  for (int c0 = 0; c0 < 256; c0 += 64) {
    for (int rep = 0; rep < 2; rep++) {
      int cc = rep * 32 + (t >> 3);
      int seg = t & 7;
#pragma unroll
      for (int u = 0; u < 4; u++) {
        int h8 = seg * 4 + u;                 // 0..31
        int bi = h8 >> 2, wq = (h8 & 3) * 8;
        half8 v = *(const half8*)(xn + ((size_t)(b * 256 + c0 + cc)) * PP + iws8[bi] * 32 + wq);
        *(half8*)&xg[cc][h8 * 8] = v;
      }
    }
    for (int rep = 0; rep < 2; rep++) {
      int idx = t + rep * 256;
      int a = idx >> 6, cc = idx & 63;
      wrow[a][cc] = (float)W16[(size_t)(512 + hd * 32 + ihs[a]) * 256 + c0 + cc];
    }
    __syncthreads();
    for (int cc = 0; cc < 64; cc++) {
      float xv = (float)xg[cc][t];
#pragma unroll
      for (int a = 0; a < 8; a++) acc[a] += wrow[a][cc] * xv;
    }
    __syncthreads();
  }
  int bi = t >> 5, w = t & 31;
#pragma unroll
  for (int a = 0; a < 8; a++)
    vsel[((size_t)bh * 64 + a * 8 + bi) * 32 + w] = acc[a];
}

// ---------------- MFMA attention ----------------
__global__ __launch_bounds__(256) void k_attn_mf(const f16* __restrict__ qk,
                                                 const float* __restrict__ vsel,
                                                 const int* __restrict__ ih,
                                                 const int* __restrict__ iw,
                                                 f16* __restrict__ o_r) {
  __shared__ f16 Ks[64][40];
  __shared__ f16 Vt[32][72];
  __shared__ f16 Ps[4][32][72];
  __shared__ f16 Os[32][136];
  __shared__ int ihs[8], iws8[8];
  int bh = blockIdx.y, b = bh >> 3, hd = bh & 7;
  int t = threadIdx.x;
  if (t < 8) { ihs[t] = ih[bh * 8 + t]; iws8[t] = iw[bh * 8 + t]; }
  __syncthreads();
  {
    int j = t >> 2, wc = (t & 3) * 8;
    const f16* kb = qk + ((size_t)(b * 512 + 256 + hd * 32 + ihs[j >> 3])) * PP
                    + iws8[j & 7] * 32 + wc;
    *(half8*)&Ks[j][wc] = *(const half8*)kb;
  }
  for (int rep = 0; rep < 2; rep++) {
    int idx = t + rep * 256;
    int j = idx >> 3, w4 = (idx & 7) * 4;
    float4 v = *(const float4*)(vsel + ((size_t)bh * 64 + j) * 32 + w4);
    Vt[w4 + 0][j] = (f16)v.x; Vt[w4 + 1][j] = (f16)v.y;
    Vt[w4 + 2][j] = (f16)v.z; Vt[w4 + 3][j] = (f16)v.w;
  }
  __syncthreads();
  int wv = t >> 6, lane = t & 63, col = lane & 15, quad = lane >> 4;
  int i0 = blockIdx.x * 128;
  int dq = i0 >> 8;
  int hb = (i0 & 255) + wv * 32;
  const f16* qbase = qk + ((size_t)(b * 512 + hd * 32 + dq)) * PP;
  f32x4 sacc[2][4];
#pragma unroll
  for (int i = 0; i < 2; i++)
#pragma unroll
    for (int j = 0; j < 4; j++) sacc[i][j] = (f32x4){0.f, 0.f, 0.f, 0.f};
#pragma unroll
  for (int mt = 0; mt < 2; mt++) {
    half8 af = *(const half8*)(qbase + (size_t)(hb + mt * 16 + col) * 32 + quad * 8);
#pragma unroll
    for (int nt = 0; nt < 4; nt++) {
      half8 bf = *(const half8*)&Ks[nt * 16 + col][quad * 8];
      sacc[mt][nt] = __builtin_amdgcn_mfma_f32_16x16x32_f16(af, bf, sacc[mt][nt], 0, 0, 0);
    }
  }
#pragma unroll
  for (int mt = 0; mt < 2; mt++) {
#pragma unroll
    for (int r = 0; r < 4; r++) {
      float s0 = sacc[mt][0][r], s1 = sacc[mt][1][r], s2 = sacc[mt][2][r], s3 = sacc[mt][3][r];
      float mx = fmaxf(fmaxf(s0, s1), fmaxf(s2, s3));
      mx = fmaxf(mx, __shfl_xor(mx, 1));
      mx = fmaxf(mx, __shfl_xor(mx, 2));
      mx = fmaxf(mx, __shfl_xor(mx, 4));
      mx = fmaxf(mx, __shfl_xor(mx, 8));
      float e0 = __expf(s0 - mx), e1 = __expf(s1 - mx), e2 = __expf(s2 - mx), e3 = __expf(s3 - mx);
      float l = e0 + e1 + e2 + e3;
      l += __shfl_xor(l, 1);
      l += __shfl_xor(l, 2);
      l += __shfl_xor(l, 4);
      l += __shfl_xor(l, 8);
      float inv = 1.0f / l;
      int row = mt * 16 + quad * 4 + r;
      Ps[wv][row][0 * 16 + col] = (f16)(e0 * inv);
      Ps[wv][row][1 * 16 + col] = (f16)(e1 * inv);
      Ps[wv][row][2 * 16 + col] = (f16)(e2 * inv);
      Ps[wv][row][3 * 16 + col] = (f16)(e3 * inv);
    }
  }
  __syncthreads();
  f32x4 oacc[2][2];
#pragma unroll
  for (int i = 0; i < 2; i++)
#pragma unroll
    for (int j = 0; j < 2; j++) oacc[i][j] = (f32x4){0.f, 0.f, 0.f, 0.f};
#pragma unroll
  for (int kk = 0; kk < 2; kk++) {
    half8 ap[2], bv[2];
#pragma unroll
    for (int mt = 0; mt < 2; mt++) ap[mt] = *(const half8*)&Ps[wv][mt * 16 + col][kk * 32 + quad * 8];
#pragma unroll
    for (int wn = 0; wn < 2; wn++) bv[wn] = *(const half8*)&Vt[wn * 16 + col][kk * 32 + quad * 8];
#pragma unroll
    for (int mt = 0; mt < 2; mt++)
#pragma unroll
      for (int wn = 0; wn < 2; wn++)
        oacc[mt][wn] = __builtin_amdgcn_mfma_f32_16x16x32_f16(ap[mt], bv[wn], oacc[mt][wn], 0, 0, 0);
  }
#pragma unroll
  for (int mt = 0; mt < 2; mt++)
#pragma unroll
    for (int wn = 0; wn < 2; wn++)
#pragma unroll
      for (int r = 0; r < 4; r++)
        Os[wn * 16 + col][wv * 32 + mt * 16 + quad * 4 + r] = (f16)oacc[mt][wn][r];
  __syncthreads();
  {
    int dd = t >> 3, seg = t & 7;
#pragma unroll
    for (int u = 0; u < 2; u++) {
      int io = (seg * 2 + u) * 8;
      *(half8*)(o_r + ((size_t)(b * 256 + hd * 32 + dd)) * PP + i0 + io) = *(const half8*)&Os[dd][io];
    }
  }
}

// ---------------- conv branch dw3x3 on x -> fp16 channels [256,512) of bv512 ----------------
__global__ __launch_bounds__(256) void k_dw(const float* __restrict__ in,
                                            const float* __restrict__ wdw,
                                            const float* __restrict__ bdw,
                                            f16* __restrict__ out) {
  int bc = blockIdx.x;
  int b = bc >> 8, c = bc & 255;
  int p = blockIdx.y * 256 + threadIdx.x;
  int x0 = p >> 5, y0 = p & 31;
  const float* ip = in + (size_t)bc * PP;
  const float* wp = wdw + c * 9;
  float s = bdw[c];
#pragma unroll
  for (int i = 0; i < 3; i++) {
    int xx = x0 + i - 1;
    if (xx < 0 || xx >= HH) continue;
#pragma unroll
    for (int j = 0; j < 3; j++) {
      int yy = y0 + j - 1;
      if (yy < 0 || yy >= WW) continue;
      s += wp[i * 3 + j] * ip[xx * 32 + yy];
    }
  }
  out[((size_t)(b * 512 + 256 + c)) * PP + p] = (f16)s;
}

// ======== fused FF inner: gelu(inorm(h1)) -> dwconv -> gelu(inorm(.)) + residual ========
// In-place safe: each block reads exactly its own (c,zz) channel into regs/LDS
// before writing it back -> h2 may alias h1.
__global__ __launch_bounds__(256) void k_ff_fused(const f16* __restrict__ h1,
                                                  const float* __restrict__ wdw,
                                                  const float* __restrict__ bdw,
                                                  f16* __restrict__ h2) {
  __shared__ float gbuf[256 * 33];
  __shared__ float redA[8], redB[8];
  int c = blockIdx.x, zz = blockIdx.y;
  int t = threadIdx.x;
  int wv = t >> 6, lane = t & 63;
  const f16* hp = h1 + ((size_t)zz * FFI + c) * PP;
  f16* out = h2 + ((size_t)zz * FFI + c) * PP;

  float v[32];
  float s = 0.f, s2 = 0.f;
#pragma unroll
  for (int u = 0; u < 4; u++) {
    half8 h = *(const half8*)(hp + (u * 256 + t) * 8);
#pragma unroll
    for (int e = 0; e < 8; e++) { float f = (float)h[e]; v[u * 8 + e] = f; s += f; s2 += f * f; }
  }
#pragma unroll
  for (int o = 32; o; o >>= 1) { s += __shfl_xor(s, o); s2 += __shfl_xor(s2, o); }
  if (lane == 0) { redA[wv] = s; redA[4 + wv] = s2; }
  __syncthreads();
  float m = (redA[0] + redA[1] + redA[2] + redA[3]) * (1.0f / PP);
  float s2a = (redA[4] + redA[5] + redA[6] + redA[7]) * (1.0f / PP);
  float r = rsqrtf(s2a - m * m + 1e-5f);

#pragma unroll
  for (int u = 0; u < 4; u++) {
    int base = (u * 256 + t) * 8;
    int row = base >> 5, colb = base & 31;
#pragma unroll
    for (int e = 0; e < 8; e++)
      gbuf[row * 33 + colb + e] = gelu_f((v[u * 8 + e] - m) * r);
  }
  __syncthreads();

  float wf[9];
#pragma unroll
  for (int i = 0; i < 9; i++) wf[i] = wdw[c * 9 + i];
  float bd = bdw[c];
  float g0[32];
#pragma unroll
  for (int y = 0; y < 32; y++) g0[y] = gbuf[t * 33 + y];
  const float* up = (t > 0) ? &gbuf[(t - 1) * 33] : nullptr;
  const float* dn = (t < 255) ? &gbuf[(t + 1) * 33] : nullptr;
  float d[32];
  float sd = 0.f, sd2 = 0.f;
#pragma unroll
  for (int y = 0; y < 32; y++) {
    float um1 = 0.f, u0 = 0.f, up1 = 0.f;
    float dm1 = 0.f, d0 = 0.f, dp1 = 0.f;
    if (up) { u0 = up[y]; if (y > 0) um1 = up[y - 1]; if (y < 31) up1 = up[y + 1]; }
    if (dn) { d0 = dn[y]; if (y > 0) dm1 = dn[y - 1]; if (y < 31) dp1 = dn[y + 1]; }
    float a = bd + wf[1] * u0 + wf[4] * g0[y] + wf[7] * d0;
    if (y > 0)  a += wf[0] * um1 + wf[3] * g0[y - 1] + wf[6] * dm1;
    if (y < 31) a += wf[2] * up1 + wf[5] * g0[y + 1] + wf[8] * dp1;
    d[y] = a; sd += a; sd2 += a * a;
  }
#pragma unroll
  for (int o = 32; o; o >>= 1) { sd += __shfl_xor(sd, o); sd2 += __shfl_xor(sd2, o); }
  if (lane == 0) { redB[wv] = sd; redB[4 + wv] = sd2; }
  __syncthreads();
  float dm = (redB[0] + redB[1] + redB[2] + redB[3]) * (1.0f / PP);
  float dv = (redB[4] + redB[5] + redB[6] + redB[7]) * (1.0f / PP);
  float dr = rsqrtf(dv - dm * dm + 1e-5f);

#pragma unroll
  for (int y = 0; y < 32; y++)
    gbuf[t * 33 + y] = g0[y] + gelu_f((d[y] - dm) * dr);
  __syncthreads();

#pragma unroll
  for (int u = 0; u < 4; u++) {
    int base = (u * 256 + t) * 8;
    int row = base >> 5, colb = base & 31;
    half8 h;
#pragma unroll
    for (int e = 0; e < 8; e++) h[e] = (f16)gbuf[row * 33 + colb + e];
    *(half8*)(out + base) = h;
  }
}

// ---------------- fp32 inorm stats + apply (final) ----------------
__global__ __launch_bounds__(256) void k_istats(const float* __restrict__ in,
                                                float* __restrict__ stm,
                                                float* __restrict__ str) {
  __shared__ float ss[256], ss2[256];
  int row = blockIdx.x, t = threadIdx.x;
  const float* p = in + (size_t)row * PP;
  float s = 0.f, s2 = 0.f;
  for (int i = t; i < PP; i += 256) { float v = p[i]; s += v; s2 += v * v; }
  ss[t] = s; ss2[t] = s2;
  __syncthreads();
  for (int off = 128; off; off >>= 1) {
    if (t < off) { ss[t] += ss[t + off]; ss2[t] += ss2[t + off]; }
    __syncthreads();
  }
  if (t == 0) {
    float m = ss[0] * (1.0f / PP);
    float var = ss2[0] * (1.0f / PP) - m * m;
    stm[row] = m;
    str[row] = rsqrtf(var + 1e-5f);
  }
}

__global__ __launch_bounds__(256) void k_napply(float* __restrict__ io,
                                                const float* __restrict__ stm,
                                                const float* __restrict__ str) {
  size_t idx = (size_t)blockIdx.x * 256 + threadIdx.x;
  int row = (int)(idx >> 13);
  io[idx] = (io[idx] - stm[row]) * str[row];
}

extern "C" void kernel_launch(void* const* d_in, const int* in_sizes, int n_in,
                              void* d_out, int out_size, void* d_ws, size_t ws_size,
                              hipStream_t stream) {
  const float* x      = (const float*)d_in[0];
  const float* cln_g  = (const float*)d_in[1];
  const float* cln_b  = (const float*)d_in[2];
  const float* w_qkv  = (const float*)d_in[3];
  const float* w_out  = (const float*)d_in[4];
  const float* b_out  = (const float*)d_in[5];
  const float* w_dw   = (const float*)d_in[6];
  const float* b_dw   = (const float*)d_in[7];
  const float* w_comb = (const float*)d_in[8];
  const float* b_comb = (const float*)d_in[9];
  const float* w_ff1  = (const float*)d_in[10];
  const float* b_ff1  = (const float*)d_in[11];
  const float* w_ffdw = (const float*)d_in[12];
  const float* b_ffdw = (const float*)d_in[13];
  const float* w_ff2  = (const float*)d_in[14];
  const float* b_ff2  = (const float*)d_in[15];
  float* outF = (float*)d_out;

  float* ws = (float*)d_ws;
  f16* qk    = (f16*)ws;
  f16* bv512 = (f16*)ws;
  f16* h1    = (f16*)ws;            // z=4 slab: 1024*8192*4*2B = 64 MiB = BIG
  f16* xn    = (f16*)d_out;
  f16* o_r   = (f16*)d_out;
  f16* combT = (f16*)d_out;
  float* qprobe = ws + OFF_QPROBE;
  float* sh     = ws + OFF_SH;
  int*   ih     = (int*)(ws + OFF_IH);
  int*   iw     = (int*)(ws + OFF_IW);
  float* stm    = ws + OFF_STM;
  float* str    = ws + OFF_STR;
  float* vsel   = ws + OFF_VSEL;
  f16*   W16    = (f16*)(ws + OFF_W16);

  // 0. weights -> fp16
  hipLaunchKernelGGL(k_wcvt, dim3(896), dim3(256), 0, stream,
                     w_qkv, w_out, w_comb, w_ff1, w_ff2, W16);
  // 1. fused channel-LN -> xn fp16 (d_out)
  hipLaunchKernelGGL(k_lnxn, dim3(256), dim3(256), 0, stream, x, cln_g, cln_b, xn);
  // 2. q,k GEMM (+l2norm) -> qk fp16 (ws); 8-wave 256m-tile, gy=2 covers M=512
  hipLaunchKernelGGL(k_mf_qk8, dim3(64, 2, 8), dim3(512), 0, stream,
                     W16 + WH_QKV, xn, (size_t)CDIM * PP, qk, 256);
  // 3. probes + top-k
  hipLaunchKernelGGL(k_probe, dim3(64), dim3(256), 0, stream, qk, qprobe, sh);
  hipLaunchKernelGGL(k_topk_h, dim3(64), dim3(64), 0, stream, sh, ih);
  hipLaunchKernelGGL(k_sw_topk, dim3(64), dim3(256), 0, stream, qk, qprobe, ih, iw);
  // 4. v at selected positions (reads xn, still live)
  hipLaunchKernelGGL(k_vsel2, dim3(64), dim3(256), 0, stream, xn, W16 + WH_QKV, ih, iw, vsel);
  // 5. MFMA attention -> o_r fp16 (d_out; xn dead)
  hipLaunchKernelGGL(k_attn_mf, dim3(64, 64), dim3(256), 0, stream, qk, vsel, ih, iw, o_r);
  // 6. attn_branch GEMM -> bv512 [0,256) (qk dead); M=256 -> gy=1
  hipLaunchKernelGGL(k_mf8, dim3(64, 1, 8), dim3(512), 0, stream,
                     W16 + WH_OUT, o_r, (size_t)CDIM * PP, bv512, (size_t)512 * PP,
                     b_out, (const float*)nullptr, (size_t)0, 256);
  // 7. conv branch -> bv512 [256,512)
  hipLaunchKernelGGL(k_dw, dim3(2048, 32), dim3(256), 0, stream, x, w_dw, b_dw, bv512);
  // 8. comb GEMM (K=512, +x residual) -> combT fp16 (d_out; o_r dead); gy=1
  hipLaunchKernelGGL(k_mf8, dim3(64, 1, 8), dim3(512), 0, stream,
                     W16 + WH_COMB, bv512, (size_t)512 * PP, combT, (size_t)CDIM * PP,
                     b_comb, x, (size_t)CDIM * PP, 512);
  // 9. FF chain in batch-quads, descending (combT-in-d_out aliasing safe:
  //    b=4 writes outF bytes [32M,64M) which never overlap combT [0,32M);
  //    b=0's FF1 reads combT [0,16M) before its FF2 writes [0,32M)).
  for (int b = 4; b >= 0; b -= 4) {
    hipLaunchKernelGGL(k_mf8, dim3(64, 4, 4), dim3(512), 0, stream,
                       W16 + WH_FF1, combT + (size_t)b * CDIM * PP, (size_t)CDIM * PP,
                       h1, (size_t)FFI * PP, b_ff1,
                       (const float*)nullptr, (size_t)0, 256);
    hipLaunchKernelGGL(k_ff_fused, dim3(FFI, 4), dim3(256), 0, stream,
                       h1, w_ffdw, b_ffdw, h1);
    hipLaunchKernelGGL(k_mf, dim3(64, 2, 4), dim3(256), 0, stream,
                       W16 + WH_FF2, h1, (size_t)FFI * PP,
                       (f16*)nullptr, outF + (size_t)b * CDIM * PP, (size_t)CDIM * PP,
                       b_ff2, (const float*)nullptr, (size_t)0, 1024);
  }
  // 10. final inorm in place on d_out
  hipLaunchKernelGGL(k_istats, dim3(2048), dim3(256), 0, stream, outF, stm, str);
  hipLaunchKernelGGL(k_napply, dim3(65536), dim3(256), 0, stream, outF, stm, str);
}

// Round 7
// 900.457 us; speedup vs baseline: 1.3569x; 1.0765x over previous
//
#include <hip/hip_runtime.h>
#include <hip/hip_fp16.h>
#include <math.h>

#define B_    8
#define CDIM  256
#define HH    256
#define WW    32
#define PP    8192
#define HEADS 8
#define FFI   1024

typedef _Float16 f16;
typedef _Float16 half8 __attribute__((ext_vector_type(8)));
typedef _Float16 half4 __attribute__((ext_vector_type(4)));
typedef _Float16 f16x2v __attribute__((ext_vector_type(2)));
typedef float f32x4 __attribute__((ext_vector_type(4)));

// soft barrier: LDS-only fence. Drains ds ops (lgkmcnt) but lets register-
// destined global prefetch loads stay in flight across the barrier.
#define SOFT_BARRIER() asm volatile("s_waitcnt lgkmcnt(0)\n\ts_barrier" ::: "memory")

// ---------------- workspace layout (float offsets) ----------------
static const size_t OFF_PPART  = 16777216;   // 64*64*32 f32 = 131072 floats (probe partials)
static const size_t OFF_QPROBE = 16908288;
static const size_t OFF_SH     = 16910336;
static const size_t OFF_IH     = 16912384;
static const size_t OFF_IW     = 16912896;
static const size_t OFF_STM    = 16913408;
static const size_t OFF_STR    = 16921600;
static const size_t OFF_VSEL   = 16929792;
static const size_t OFF_W16    = 17060864;   // 917504 halves = 458752 floats

// fp16 weight region offsets (in halves)
#define WH_QKV  0
#define WH_OUT  196608
#define WH_COMB 262144
#define WH_FF1  393216
#define WH_FF2  655360

// fast gelu: x*Phi(x) via A&S 7.1.26 erf, |erf err| <= 1.5e-7, branchless.
__device__ __forceinline__ float gelu_f(float x) {
  float z = fabsf(x) * 0.70710678118f;
  float t = __builtin_amdgcn_rcpf(1.0f + 0.3275911f * z);
  float poly = t * (0.254829592f +
               t * (-0.284496736f +
               t * (1.421413741f +
               t * (-1.453152027f +
               t * 1.061405429f))));
  float e = 1.0f - poly * __expf(-z * z);
  return 0.5f * x * (1.0f + copysignf(e, x));
}

// ---------------- weights -> fp16 ----------------
__global__ __launch_bounds__(256) void k_wcvt(const float* __restrict__ s0,
                                              const float* __restrict__ s1,
                                              const float* __restrict__ s2,
                                              const float* __restrict__ s3,
                                              const float* __restrict__ s4,
                                              f16* __restrict__ dst) {
  int blk = blockIdx.x;   // 896 blocks x 1024 elems
  const float* src; size_t base;
  if (blk < 192)      { src = s0; base = WH_QKV;  }
  else if (blk < 256) { src = s1; base = WH_OUT;  blk -= 192; }
  else if (blk < 384) { src = s2; base = WH_COMB; blk -= 256; }
  else if (blk < 640) { src = s3; base = WH_FF1;  blk -= 384; }
  else                { src = s4; base = WH_FF2;  blk -= 640; }
  int off = blk * 1024 + threadIdx.x * 4;
  float4 v = *(const float4*)(src + off);
  half4 h; h[0] = (f16)v.x; h[1] = (f16)v.y; h[2] = (f16)v.z; h[3] = (f16)v.w;
  *(half4*)(dst + base + off) = h;
}

// ---------------- fused channel-LN -> xn fp16 ----------------
__global__ __launch_bounds__(256) void k_lnxn(const float* __restrict__ x,
                                              const float* __restrict__ g,
                                              const float* __restrict__ bb,
                                              f16* __restrict__ xn) {
  int idx = blockIdx.x * 256 + threadIdx.x;      // 65536 = b*PP + p
  int b = idx >> 13, p = idx & 8191;
  const float* xp = x + (size_t)b * CDIM * PP + p;
  float s = 0.f, s2 = 0.f;
  for (int c = 0; c < CDIM; c++) { float v = xp[(size_t)c * PP]; s += v; s2 += v * v; }
  float m = s * (1.0f / CDIM);
  float var = s2 * (1.0f / CDIM) - m * m;
  float r = rsqrtf(var + 1e-5f);
  f16* xo = xn + (size_t)b * CDIM * PP + p;
  for (int c = 0; c < CDIM; c++)
    xo[(size_t)c * PP] = (f16)((xp[(size_t)c * PP] - m) * r * g[c] + bb[c]);
}

// ================= MFMA fp16 GEMM, 1-m-tile 256-thread (FF2 float-out) =================
#define MF_STAGE                                                                   \
  int t = threadIdx.x;                                                             \
  int nw_ = gridDim.x * gridDim.y;                                                 \
  int hb_ = blockIdx.x + gridDim.x * blockIdx.y;                                   \
  int wk_ = (hb_ & 7) * (nw_ >> 3) + (hb_ >> 3);                                   \
  int gy_ = gridDim.y;                                                             \
  int sh_ = __ffs(gy_) - 1;                                                        \
  int p0 = (wk_ >> sh_) * 128, m0 = (wk_ & (gy_ - 1)) * 128, z = blockIdx.z;       \
  int lane = t & 63, wave = t >> 6;                                                \
  int wm = (wave >> 1) * 64, wp = (wave & 1) * 64;                                 \
  int col = lane & 15, quad = lane >> 4;                                           \
  f32x4 acc[4][4];                                                                 \
  _Pragma("unroll") for (int i = 0; i < 4; i++)                                    \
  _Pragma("unroll") for (int j = 0; j < 4; j++)                                    \
      acc[i][j] = (f32x4){0.f, 0.f, 0.f, 0.f};                                     \
  int am = t >> 1, ak = (t & 1) * 16;                                              \
  int bp = (t & 15) * 8, bk = (t >> 4) * 2;                                        \
  int erot = t & 7;                                                                \
  const f16* wr0 = W + (size_t)(m0 + am) * K + ak;                                 \
  const f16* br0 = inB + (size_t)bk * PP + p0 + bp;                                \
  half8 w0 = *(const half8*)wr0;                                                   \
  half8 w1 = *(const half8*)(wr0 + 8);                                             \
  half8 r0 = *(const half8*)br0;                                                   \
  half8 r1 = *(const half8*)(br0 + PP);                                            \
  for (int k0 = 0; k0 < K; k0 += 32) {                                             \
    *(half8*)&As[am][ak] = w0;                                                     \
    *(half8*)&As[am][ak + 8] = w1;                                                 \
    _Pragma("unroll") for (int e0 = 0; e0 < 8; e0++) {                             \
      int e = (e0 + erot) & 7;                                                     \
      f16x2v pr2; pr2[0] = r0[e]; pr2[1] = r1[e];                                  \
      *(f16x2v*)&Bs[bp + e][bk] = pr2;                                             \
    }                                                                              \
    SOFT_BARRIER();                                                                \
    int kn = (k0 + 32 < K) ? k0 + 32 : k0;                                         \
    w0 = *(const half8*)(wr0 + kn);                                                \
    w1 = *(const half8*)(wr0 + kn + 8);                                            \
    r0 = *(const half8*)(inB + (size_t)(kn + bk) * PP + p0 + bp);                  \
    r1 = *(const half8*)(inB + (size_t)(kn + bk + 1) * PP + p0 + bp);              \
    half8 af[4], bf[4];                                                            \
    _Pragma("unroll") for (int i = 0; i < 4; i++)                                  \
      af[i] = *(const half8*)&As[wm + i * 16 + col][quad * 8];                     \
    _Pragma("unroll") for (int j = 0; j < 4; j++)                                  \
      bf[j] = *(const half8*)&Bs[wp + j * 16 + col][quad * 8];                     \
    _Pragma("unroll") for (int i = 0; i < 4; i++)                                  \
    _Pragma("unroll") for (int j = 0; j < 4; j++)                                  \
        acc[i][j] = __builtin_amdgcn_mfma_f32_16x16x32_f16(af[i], bf[j],           \
                                                           acc[i][j], 0, 0, 0);    \
    SOFT_BARRIER();                                                                \
  }

__global__ __launch_bounds__(256) void k_mf(const f16* __restrict__ W,
                                            const f16* __restrict__ In, size_t inZ,
                                            f16* __restrict__ OutH,
                                            float* __restrict__ OutF, size_t outZ,
                                            const float* __restrict__ bias,
                                            const float* __restrict__ resid, size_t residZ,
                                            int K) {
  __shared__ f16 As[128][40];
  __shared__ f16 Bs[128][40];
  const f16* inB = In + (size_t)blockIdx.z * inZ;
  MF_STAGE
#pragma unroll
  for (int i = 0; i < 4; i++) {
    int mb = m0 + wm + i * 16 + quad * 4;
#pragma unroll
    for (int r = 0; r < 4; r++) {
      int m = mb + r;
      float bs = bias ? bias[m] : 0.f;
#pragma unroll
      for (int j = 0; j < 4; j++) {
        int p = p0 + wp + j * 16 + col;
        float v = acc[i][j][r] + bs;
        size_t off = (size_t)z * outZ + (size_t)m * PP + p;
        if (resid) v += resid[(size_t)z * residZ + (size_t)m * PP + p];
        if (OutF) OutF[off] = v;
        else OutH[off] = (f16)v;
      }
    }
  }
}

// ========== 8-wave MFMA GEMM: 256m x 128p per block, 512 threads ==========
#define MF_STAGE8                                                                  \
  int t = threadIdx.x;                                                             \
  int nw_ = gridDim.x * gridDim.y;                                                 \
  int hb_ = blockIdx.x + gridDim.x * blockIdx.y;                                   \
  int wk_ = (hb_ & 7) * (nw_ >> 3) + (hb_ >> 3);                                   \
  int gy_ = gridDim.y;                                                             \
  int sh_ = __ffs(gy_) - 1;                                                        \
  int p0 = (wk_ >> sh_) * 128, m0 = (wk_ & (gy_ - 1)) * 256, z = blockIdx.z;       \
  int lane = t & 63, wave = t >> 6;                                                \
  int wm = (wave >> 1) * 64, wp = (wave & 1) * 64;                                 \
  int col = lane & 15, quad = lane >> 4;                                           \
  f32x4 acc[4][4];                                                                 \
  _Pragma("unroll") for (int i = 0; i < 4; i++)                                    \
  _Pragma("unroll") for (int j = 0; j < 4; j++)                                    \
      acc[i][j] = (f32x4){0.f, 0.f, 0.f, 0.f};                                     \
  int am = t >> 1, ak = (t & 1) * 16;                                              \
  int bp = (t & 15) * 8, bk = (t >> 4) * 2;   /* B-staging valid for t<256 */      \
  int erot = t & 7;                                                                \
  const f16* wr0 = W + (size_t)(m0 + am) * K + ak;                                 \
  const f16* br0 = inB + (size_t)(bk & 31) * PP + p0 + bp;                         \
  half8 w0 = *(const half8*)wr0;                                                   \
  half8 w1 = *(const half8*)(wr0 + 8);                                             \
  half8 r0 = {}, r1 = {};                                                          \
  if (t < 256) { r0 = *(const half8*)br0; r1 = *(const half8*)(br0 + PP); }        \
  for (int k0 = 0; k0 < K; k0 += 32) {                                             \
    *(half8*)&As[am][ak] = w0;                                                     \
    *(half8*)&As[am][ak + 8] = w1;                                                 \
    if (t < 256) {                                                                 \
      _Pragma("unroll") for (int e0 = 0; e0 < 8; e0++) {                           \
        int e = (e0 + erot) & 7;                                                   \
        f16x2v pr2; pr2[0] = r0[e]; pr2[1] = r1[e];                                \
        *(f16x2v*)&Bs[bp + e][bk] = pr2;                                           \
      }                                                                            \
    }                                                                              \
    SOFT_BARRIER();                                                                \
    int kn = (k0 + 32 < K) ? k0 + 32 : k0;                                         \
    w0 = *(const half8*)(wr0 + kn);                                                \
    w1 = *(const half8*)(wr0 + kn + 8);                                            \
    if (t < 256) {                                                                 \
      r0 = *(const half8*)(inB + (size_t)(kn + bk) * PP + p0 + bp);                \
      r1 = *(const half8*)(inB + (size_t)(kn + bk + 1) * PP + p0 + bp);            \
    }                                                                              \
    half8 af[4], bf[4];                                                            \
    _Pragma("unroll") for (int i = 0; i < 4; i++)                                  \
      af[i] = *(const half8*)&As[wm + i * 16 + col][quad * 8];                     \
    _Pragma("unroll") for (int j = 0; j < 4; j++)                                  \
      bf[j] = *(const half8*)&Bs[wp + j * 16 + col][quad * 8];                     \
    _Pragma("unroll") for (int i = 0; i < 4; i++)                                  \
    _Pragma("unroll") for (int j = 0; j < 4; j++)                                  \
        acc[i][j] = __builtin_amdgcn_mfma_f32_16x16x32_f16(af[i], bf[j],           \
                                                           acc[i][j], 0, 0, 0);    \
    SOFT_BARRIER();                                                                \
  }

__global__ __launch_bounds__(512) void k_mf8(const f16* __restrict__ W,
                                             const f16* __restrict__ In, size_t inZ,
                                             f16* __restrict__ OutH, size_t outZ,
                                             const float* __restrict__ bias,
                                             const float* __restrict__ resid, size_t residZ,
                                             int K) {
  __shared__ f16 As[256][40];
  __shared__ f16 Bs[128][40];
  const f16* inB = In + (size_t)blockIdx.z * inZ;
  MF_STAGE8
#pragma unroll
  for (int i = 0; i < 4; i++) {
    int mb = m0 + wm + i * 16 + quad * 4;   // wm spans 0..192 across 8 waves
#pragma unroll
    for (int r = 0; r < 4; r++) {
      int m = mb + r;
      float bs = bias ? bias[m] : 0.f;
#pragma unroll
      for (int j = 0; j < 4; j++) {
        int p = p0 + wp + j * 16 + col;
        float v = acc[i][j][r] + bs;
        size_t off = (size_t)z * outZ + (size_t)m * PP + p;
        if (resid) v += resid[(size_t)z * residZ + (size_t)m * PP + p];
        OutH[off] = (f16)v;
      }
    }
  }
}

// qk GEMM (8-wave): epilogue l2-normalizes groups of 32 consecutive p, stores fp16
__global__ __launch_bounds__(512) void k_mf_qk8(const f16* __restrict__ W,
                                                const f16* __restrict__ In, size_t inZ,
                                                f16* __restrict__ qkO, int K) {
  __shared__ f16 As[256][40];
  __shared__ f16 Bs[128][40];
  const f16* inB = In + (size_t)blockIdx.z * inZ;
  MF_STAGE8
#pragma unroll
  for (int i = 0; i < 4; i++) {
    int mb = m0 + wm + i * 16 + quad * 4;
#pragma unroll
    for (int r = 0; r < 4; r++) {
      int m = mb + r;
      size_t base = (size_t)z * 512 * PP + (size_t)m * PP;
#pragma unroll
      for (int jp = 0; jp < 2; jp++) {
        float a0 = acc[i][2 * jp][r], a1 = acc[i][2 * jp + 1][r];
        float ss = a0 * a0 + a1 * a1;
        ss += __shfl_xor(ss, 1);
        ss += __shfl_xor(ss, 2);
        ss += __shfl_xor(ss, 4);
        ss += __shfl_xor(ss, 8);
        float inv = 1.0f / fmaxf(sqrtf(ss), 1e-12f);
        int pa = p0 + wp + 2 * jp * 16 + col;
        qkO[base + pa] = (f16)(a0 * inv);
        qkO[base + pa + 16] = (f16)(a1 * inv);
      }
    }
  }
}

// ---------------- probe partials: one block per (bh, row) ----------------
// y<32: q row d=y of head (b,hd); y>=32: k row d=y-32. Sums over h (256) for
// each w (32) -> part[bh][y][w]. 4096 blocks -> HBM-bound.
__global__ __launch_bounds__(256) void k_psum(const f16* __restrict__ qk,
                                              float* __restrict__ part) {
  __shared__ float red[64][32];
  int bh = blockIdx.x, y = blockIdx.y;
  int b = bh >> 3, hd = bh & 7;
  int t = threadIdx.x;
  int row = (y < 32) ? (b * 512 + hd * 32 + y)
                     : (b * 512 + 256 + hd * 32 + (y - 32));
  const f16* rp = qk + (size_t)row * PP;
  int g = t >> 2, w8 = (t & 3) * 8;
  float s[8];
#pragma unroll
  for (int e = 0; e < 8; e++) s[e] = 0.f;
  for (int h = g; h < 256; h += 64) {
    half8 v = *(const half8*)(rp + h * 32 + w8);
#pragma unroll
    for (int e = 0; e < 8; e++) s[e] += (float)v[e];
  }
#pragma unroll
  for (int e = 0; e < 8; e++) red[g][w8 + e] = s[e];
  __syncthreads();
  if (t < 32) {
    float a = 0.f;
    for (int gg = 0; gg < 64; gg++) a += red[gg][t];
    part[((size_t)bh * 64 + y) * 32 + t] = a;
  }
}

// ---------------- probe finish: qp, sh = qp . ksum, top-k(8) ----------------
__global__ __launch_bounds__(64) void k_pfin(const float* __restrict__ part,
                                             float* __restrict__ qprobe,
                                             int* __restrict__ ih) {
  __shared__ float qps[32], shs[32];
  int bh = blockIdx.x, t = threadIdx.x;
  const float* pb = part + (size_t)bh * 2048;
  if (t < 32) {
    float a = 0.f;
    for (int d = 0; d < 32; d++) a += pb[d * 32 + t];
    qps[t] = a;
    qprobe[bh * 32 + t] = a;
  }
  __syncthreads();
  if (t < 32) {
    float a = 0.f;
    const float* kp = pb + (size_t)(32 + t) * 32;
    for (int w = 0; w < 32; w++) a += qps[w] * kp[w];
    shs[t] = a;
  }
  __syncthreads();
  if (t == 0) {
    for (int s = 0; s < 8; s++) {
      int bi = 0; float bv = shs[0];
      for (int i = 1; i < 32; i++) { if (shs[i] > bv) { bv = shs[i]; bi = i; } }
      ih[bh * 8 + s] = bi;
      shs[bi] = -3.4e38f;
    }
  }
}

__global__ __launch_bounds__(256) void k_sw_topk(const f16* __restrict__ qk,
                                                 const float* __restrict__ qprobe,
                                                 const int* __restrict__ ih,
                                                 int* __restrict__ iw) {
  __shared__ float qp[32];
  __shared__ float sw[256];
  __shared__ int ihs[8];
  int bh = blockIdx.x, b = bh >> 3, hd = bh & 7;
  int t = threadIdx.x;
  if (t < 32) qp[t] = qprobe[bh * 32 + t];
  if (t < 8) ihs[t] = ih[bh * 8 + t];
  __syncthreads();
  const f16* kb = qk + ((size_t)(b * 512 + 256 + hd * 32)) * PP;
  float s = 0.f;
  for (int a = 0; a < 8; a++) {
    const f16* kd = kb + (size_t)ihs[a] * PP + t * 32;
#pragma unroll
    for (int w = 0; w < 32; w++) s += qp[w] * (float)kd[w];
  }
  sw[t] = s;
  __syncthreads();
  if (t == 0) {
    for (int sel = 0; sel < 8; sel++) {
      int bi = 0; float bv = sw[0];
      for (int i = 1; i < 256; i++) { if (sw[i] > bv) { bv = sw[i]; bi = i; } }
      iw[bh * 8 + sel] = bi;
      sw[bi] = -3.4e38f;
    }
  }
}

// ---------------- v at selected positions, LDS-staged from xn fp16 ----------------
__global__ __launch_bounds__(256) void k_vsel2(const f16* __restrict__ xn,
                                               const f16* __restrict__ W16,
                                               const int* __restrict__ ih,
                                               const int* __restrict__ iw,
                                               float* __restrict__ vsel) {
  __shared__ f16 xg[64][264];
  __shared__ float wrow[8][64];
  __shared__ int ihs[8], iws8[8];
  int bh = blockIdx.x, b = bh >> 3, hd = bh & 7;
  int t = threadIdx.x;
  if (t < 8) { ihs[t] = ih[bh * 8 + t]; iws8[t] = iw[bh * 8 + t]; }
  __syncthreads();
  float acc[8];
#pragma unroll
  for (int a = 0; a < 8; a++) acc[a] = 0.f;
  for (int c0 = 0; c0 < 256; c0 += 64) {
    for (int rep = 0; rep < 2; rep++) {
      int cc = rep * 32 + (t >> 3);
      int seg = t & 7;
#pragma unroll
      for (int u = 0; u < 4; u++) {
        int h8 = seg * 4 + u;                 // 0..31
        int bi = h8 >> 2, wq = (h8 & 3) * 8;
        half8 v = *(const half8*)(xn + ((size_t)(b * 256 + c0 + cc)) * PP + iws8[bi] * 32 + wq);
        *(half8*)&xg[cc][h8 * 8] = v;
      }
    }
    for (int rep = 0; rep < 2; rep++) {
      int idx = t + rep * 256;
      int a = idx >> 6, cc = idx & 63;
      wrow[a][cc] = (float)W16[(size_t)(512 + hd * 32 + ihs[a]) * 256 + c0 + cc];
    }
    __syncthreads();
    for (int cc = 0; cc < 64; cc++) {
      float xv = (float)xg[cc][t];
#pragma unroll
      for (int a = 0; a < 8; a++) acc[a] += wrow[a][cc] * xv;
    }
    __syncthreads();
  }
  int bi = t >> 5, w = t & 31;
#pragma unroll
  for (int a = 0; a < 8; a++)
    vsel[((size_t)bh * 64 + a * 8 + bi) * 32 + w] = acc[a];
}

// ---------------- MFMA attention ----------------
__global__ __launch_bounds__(256) void k_attn_mf(const f16* __restrict__ qk,
                                                 const float* __restrict__ vsel,
                                                 const int* __restrict__ ih,
                                                 const int* __restrict__ iw,
                                                 f16* __restrict__ o_r) {
  __shared__ f16 Ks[64][40];
  __shared__ f16 Vt[32][72];
  __shared__ f16 Ps[4][32][72];
  __shared__ f16 Os[32][136];
  __shared__ int ihs[8], iws8[8];
  int bh = blockIdx.y, b = bh >> 3, hd = bh & 7;
  int t = threadIdx.x;
  if (t < 8) { ihs[t] = ih[bh * 8 + t]; iws8[t] = iw[bh * 8 + t]; }
  __syncthreads();
  {
    int j = t >> 2, wc = (t & 3) * 8;
    const f16* kb = qk + ((size_t)(b * 512 + 256 + hd * 32 + ihs[j >> 3])) * PP
                    + iws8[j & 7] * 32 + wc;
    *(half8*)&Ks[j][wc] = *(const half8*)kb;
  }
  for (int rep = 0; rep < 2; rep++) {
    int idx = t + rep * 256;
    int j = idx >> 3, w4 = (idx & 7) * 4;
    float4 v = *(const float4*)(vsel + ((size_t)bh * 64 + j) * 32 + w4);
    Vt[w4 + 0][j] = (f16)v.x; Vt[w4 + 1][j] = (f16)v.y;
    Vt[w4 + 2][j] = (f16)v.z; Vt[w4 + 3][j] = (f16)v.w;
  }
  __syncthreads();
  int wv = t >> 6, lane = t & 63, col = lane & 15, quad = lane >> 4;
  int i0 = blockIdx.x * 128;
  int dq = i0 >> 8;
  int hb = (i0 & 255) + wv * 32;
  const f16* qbase = qk + ((size_t)(b * 512 + hd * 32 + dq)) * PP;
  f32x4 sacc[2][4];
#pragma unroll
  for (int i = 0; i < 2; i++)
#pragma unroll
    for (int j = 0; j < 4; j++) sacc[i][j] = (f32x4){0.f, 0.f, 0.f, 0.f};
#pragma unroll
  for (int mt = 0; mt < 2; mt++) {
    half8 af = *(const half8*)(qbase + (size_t)(hb + mt * 16 + col) * 32 + quad * 8);
#pragma unroll
    for (int nt = 0; nt < 4; nt++) {
      half8 bf = *(const half8*)&Ks[nt * 16 + col][quad * 8];
      sacc[mt][nt] = __builtin_amdgcn_mfma_f32_16x16x32_f16(af, bf, sacc[mt][nt], 0, 0, 0);
    }
  }
#pragma unroll
  for (int mt = 0; mt < 2; mt++) {
#pragma unroll
    for (int r = 0; r < 4; r++) {
      float s0 = sacc[mt][0][r], s1 = sacc[mt][1][r], s2 = sacc[mt][2][r], s3 = sacc[mt][3][r];
      float mx = fmaxf(fmaxf(s0, s1), fmaxf(s2, s3));
      mx = fmaxf(mx, __shfl_xor(mx, 1));
      mx = fmaxf(mx, __shfl_xor(mx, 2));
      mx = fmaxf(mx, __shfl_xor(mx, 4));
      mx = fmaxf(mx, __shfl_xor(mx, 8));
      float e0 = __expf(s0 - mx), e1 = __expf(s1 - mx), e2 = __expf(s2 - mx), e3 = __expf(s3 - mx);
      float l = e0 + e1 + e2 + e3;
      l += __shfl_xor(l, 1);
      l += __shfl_xor(l, 2);
      l += __shfl_xor(l, 4);
      l += __shfl_xor(l, 8);
      float inv = 1.0f / l;
      int row = mt * 16 + quad * 4 + r;
      Ps[wv][row][0 * 16 + col] = (f16)(e0 * inv);
      Ps[wv][row][1 * 16 + col] = (f16)(e1 * inv);
      Ps[wv][row][2 * 16 + col] = (f16)(e2 * inv);
      Ps[wv][row][3 * 16 + col] = (f16)(e3 * inv);
    }
  }
  __syncthreads();
  f32x4 oacc[2][2];
#pragma unroll
  for (int i = 0; i < 2; i++)
#pragma unroll
    for (int j = 0; j < 2; j++) oacc[i][j] = (f32x4){0.f, 0.f, 0.f, 0.f};
#pragma unroll
  for (int kk = 0; kk < 2; kk++) {
    half8 ap[2], bv[2];
#pragma unroll
    for (int mt = 0; mt < 2; mt++) ap[mt] = *(const half8*)&Ps[wv][mt * 16 + col][kk * 32 + quad * 8];
#pragma unroll
    for (int wn = 0; wn < 2; wn++) bv[wn] = *(const half8*)&Vt[wn * 16 + col][kk * 32 + quad * 8];
#pragma unroll
    for (int mt = 0; mt < 2; mt++)
#pragma unroll
      for (int wn = 0; wn < 2; wn++)
        oacc[mt][wn] = __builtin_amdgcn_mfma_f32_16x16x32_f16(ap[mt], bv[wn], oacc[mt][wn], 0, 0, 0);
  }
#pragma unroll
  for (int mt = 0; mt < 2; mt++)
#pragma unroll
    for (int wn = 0; wn < 2; wn++)
#pragma unroll
      for (int r = 0; r < 4; r++)
        Os[wn * 16 + col][wv * 32 + mt * 16 + quad * 4 + r] = (f16)oacc[mt][wn][r];
  __syncthreads();
  {
    int dd = t >> 3, seg = t & 7;
#pragma unroll
    for (int u = 0; u < 2; u++) {
      int io = (seg * 2 + u) * 8;
      *(half8*)(o_r + ((size_t)(b * 256 + hd * 32 + dd)) * PP + i0 + io) = *(const half8*)&Os[dd][io];
    }
  }
}

// ---------------- conv branch dw3x3 on x -> fp16 channels [256,512) of bv512 ----------------
__global__ __launch_bounds__(256) void k_dw(const float* __restrict__ in,
                                            const float* __restrict__ wdw,
                                            const float* __restrict__ bdw,
                                            f16* __restrict__ out) {
  int bc = blockIdx.x;
  int b = bc >> 8, c = bc & 255;
  int p = blockIdx.y * 256 + threadIdx.x;
  int x0 = p >> 5, y0 = p & 31;
  const float* ip = in + (size_t)bc * PP;
  const float* wp = wdw + c * 9;
  float s = bdw[c];
#pragma unroll
  for (int i = 0; i < 3; i++) {
    int xx = x0 + i - 1;
    if (xx < 0 || xx >= HH) continue;
#pragma unroll
    for (int j = 0; j < 3; j++) {
      int yy = y0 + j - 1;
      if (yy < 0 || yy >= WW) continue;
      s += wp[i * 3 + j] * ip[xx * 32 + yy];
    }
  }
  out[((size_t)(b * 512 + 256 + c)) * PP + p] = (f16)s;
}

// ======== fused FF inner: gelu(inorm(h1)) -> dwconv -> gelu(inorm(.)) + residual ========
// In-place safe: each block reads exactly its own (c,zz) channel before writing it.
__global__ __launch_bounds__(256) void k_ff_fused(const f16* __restrict__ h1,
                                                  const float* __restrict__ wdw,
                                                  const float* __restrict__ bdw,
                                                  f16* __restrict__ h2) {
  __shared__ float gbuf[256 * 33];
  __shared__ float redA[8], redB[8];
  int c = blockIdx.x, zz = blockIdx.y;
  int t = threadIdx.x;
  int wv = t >> 6, lane = t & 63;
  const f16* hp = h1 + ((size_t)zz * FFI + c) * PP;
  f16* out = h2 + ((size_t)zz * FFI + c) * PP;

  float v[32];
  float s = 0.f, s2 = 0.f;
#pragma unroll
  for (int u = 0; u < 4; u++) {
    half8 h = *(const half8*)(hp + (u * 256 + t) * 8);
#pragma unroll
    for (int e = 0; e < 8; e++) { float f = (float)h[e]; v[u * 8 + e] = f; s += f; s2 += f * f; }
  }
#pragma unroll
  for (int o = 32; o; o >>= 1) { s += __shfl_xor(s, o); s2 += __shfl_xor(s2, o); }
  if (lane == 0) { redA[wv] = s; redA[4 + wv] = s2; }
  __syncthreads();
  float m = (redA[0] + redA[1] + redA[2] + redA[3]) * (1.0f / PP);
  float s2a = (redA[4] + redA[5] + redA[6] + redA[7]) * (1.0f / PP);
  float r = rsqrtf(s2a - m * m + 1e-5f);

#pragma unroll
  for (int u = 0; u < 4; u++) {
    int base = (u * 256 + t) * 8;
    int row = base >> 5, colb = base & 31;
#pragma unroll
    for (int e = 0; e < 8; e++)
      gbuf[row * 33 + colb + e] = gelu_f((v[u * 8 + e] - m) * r);
  }
  __syncthreads();

  float wf[9];
#pragma unroll
  for (int i = 0; i < 9; i++) wf[i] = wdw[c * 9 + i];
  float bd = bdw[c];
  float g0[32];
#pragma unroll
  for (int y = 0; y < 32; y++) g0[y] = gbuf[t * 33 + y];
  const float* up = (t > 0) ? &gbuf[(t - 1) * 33] : nullptr;
  const float* dn = (t < 255) ? &gbuf[(t + 1) * 33] : nullptr;
  float d[32];
  float sd = 0.f, sd2 = 0.f;
#pragma unroll
  for (int y = 0; y < 32; y++) {
    float um1 = 0.f, u0 = 0.f, up1 = 0.f;
    float dm1 = 0.f, d0 = 0.f, dp1 = 0.f;
    if (up) { u0 = up[y]; if (y > 0) um1 = up[y - 1]; if (y < 31) up1 = up[y + 1]; }
    if (dn) { d0 = dn[y]; if (y > 0) dm1 = dn[y - 1]; if (y < 31) dp1 = dn[y + 1]; }
    float a = bd + wf[1] * u0 + wf[4] * g0[y] + wf[7] * d0;
    if (y > 0)  a += wf[0] * um1 + wf[3] * g0[y - 1] + wf[6] * dm1;
    if (y < 31) a += wf[2] * up1 + wf[5] * g0[y + 1] + wf[8] * dp1;
    d[y] = a; sd += a; sd2 += a * a;
  }
#pragma unroll
  for (int o = 32; o; o >>= 1) { sd += __shfl_xor(sd, o); sd2 += __shfl_xor(sd2, o); }
  if (lane == 0) { redB[wv] = sd; redB[4 + wv] = sd2; }
  __syncthreads();
  float dm = (redB[0] + redB[1] + redB[2] + redB[3]) * (1.0f / PP);
  float dv = (redB[4] + redB[5] + redB[6] + redB[7]) * (1.0f / PP);
  float dr = rsqrtf(dv - dm * dm + 1e-5f);

#pragma unroll
  for (int y = 0; y < 32; y++)
    gbuf[t * 33 + y] = g0[y] + gelu_f((d[y] - dm) * dr);
  __syncthreads();

#pragma unroll
  for (int u = 0; u < 4; u++) {
    int base = (u * 256 + t) * 8;
    int row = base >> 5, colb = base & 31;
    half8 h;
#pragma unroll
    for (int e = 0; e < 8; e++) h[e] = (f16)gbuf[row * 33 + colb + e];
    *(half8*)(out + base) = h;
  }
}

// ---------------- fp32 inorm stats + apply (final) ----------------
__global__ __launch_bounds__(256) void k_istats(const float* __restrict__ in,
                                                float* __restrict__ stm,
                                                float* __restrict__ str) {
  __shared__ float ss[256], ss2[256];
  int row = blockIdx.x, t = threadIdx.x;
  const float* p = in + (size_t)row * PP;
  float s = 0.f, s2 = 0.f;
  for (int i = t; i < PP; i += 256) { float v = p[i]; s += v; s2 += v * v; }
  ss[t] = s; ss2[t] = s2;
  __syncthreads();
  for (int off = 128; off; off >>= 1) {
    if (t < off) { ss[t] += ss[t + off]; ss2[t] += ss2[t + off]; }
    __syncthreads();
  }
  if (t == 0) {
    float m = ss[0] * (1.0f / PP);
    float var = ss2[0] * (1.0f / PP) - m * m;
    stm[row] = m;
    str[row] = rsqrtf(var + 1e-5f);
  }
}

__global__ __launch_bounds__(256) void k_napply(float* __restrict__ io,
                                                const float* __restrict__ stm,
                                                const float* __restrict__ str) {
  size_t idx = (size_t)blockIdx.x * 256 + threadIdx.x;
  int row = (int)(idx >> 13);
  io[idx] = (io[idx] - stm[row]) * str[row];
}

extern "C" void kernel_launch(void* const* d_in, const int* in_sizes, int n_in,
                              void* d_out, int out_size, void* d_ws, size_t ws_size,
                              hipStream_t stream) {
  const float* x      = (const float*)d_in[0];
  const float* cln_g  = (const float*)d_in[1];
  const float* cln_b  = (const float*)d_in[2];
  const float* w_qkv  = (const float*)d_in[3];
  const float* w_out  = (const float*)d_in[4];
  const float* b_out  = (const float*)d_in[5];
  const float* w_dw   = (const float*)d_in[6];
  const float* b_dw   = (const float*)d_in[7];
  const float* w_comb = (const float*)d_in[8];
  const float* b_comb = (const float*)d_in[9];
  const float* w_ff1  = (const float*)d_in[10];
  const float* b_ff1  = (const float*)d_in[11];
  const float* w_ffdw = (const float*)d_in[12];
  const float* b_ffdw = (const float*)d_in[13];
  const float* w_ff2  = (const float*)d_in[14];
  const float* b_ff2  = (const float*)d_in[15];
  float* outF = (float*)d_out;

  float* ws = (float*)d_ws;
  f16* qk    = (f16*)ws;
  f16* bv512 = (f16*)ws;
  f16* h1    = (f16*)ws;            // z=4 slab: 1024*8192*4*2B = 64 MiB = BIG
  f16* xn    = (f16*)d_out;
  f16* o_r   = (f16*)d_out;
  f16* combT = (f16*)d_out;
  float* ppart  = ws + OFF_PPART;
  float* qprobe = ws + OFF_QPROBE;
  int*   ih     = (int*)(ws + OFF_IH);
  int*   iw     = (int*)(ws + OFF_IW);
  float* stm    = ws + OFF_STM;
  float* str    = ws + OFF_STR;
  float* vsel   = ws + OFF_VSEL;
  f16*   W16    = (f16*)(ws + OFF_W16);

  // 0. weights -> fp16
  hipLaunchKernelGGL(k_wcvt, dim3(896), dim3(256), 0, stream,
                     w_qkv, w_out, w_comb, w_ff1, w_ff2, W16);
  // 1. fused channel-LN -> xn fp16 (d_out)
  hipLaunchKernelGGL(k_lnxn, dim3(256), dim3(256), 0, stream, x, cln_g, cln_b, xn);
  // 2. q,k GEMM (+l2norm) -> qk fp16 (ws); 8-wave 256m-tile, gy=2 covers M=512
  hipLaunchKernelGGL(k_mf_qk8, dim3(64, 2, 8), dim3(512), 0, stream,
                     W16 + WH_QKV, xn, (size_t)CDIM * PP, qk, 256);
  // 3. probes + top-k (parallelized: 4096-block partial sums + 64-block finish)
  hipLaunchKernelGGL(k_psum, dim3(64, 64), dim3(256), 0, stream, qk, ppart);
  hipLaunchKernelGGL(k_pfin, dim3(64), dim3(64), 0, stream, ppart, qprobe, ih);
  hipLaunchKernelGGL(k_sw_topk, dim3(64), dim3(256), 0, stream, qk, qprobe, ih, iw);
  // 4. v at selected positions (reads xn, still live)
  hipLaunchKernelGGL(k_vsel2, dim3(64), dim3(256), 0, stream, xn, W16 + WH_QKV, ih, iw, vsel);
  // 5. MFMA attention -> o_r fp16 (d_out; xn dead)
  hipLaunchKernelGGL(k_attn_mf, dim3(64, 64), dim3(256), 0, stream, qk, vsel, ih, iw, o_r);
  // 6. attn_branch GEMM -> bv512 [0,256) (qk dead); M=256 -> gy=1
  hipLaunchKernelGGL(k_mf8, dim3(64, 1, 8), dim3(512), 0, stream,
                     W16 + WH_OUT, o_r, (size_t)CDIM * PP, bv512, (size_t)512 * PP,
                     b_out, (const float*)nullptr, (size_t)0, 256);
  // 7. conv branch -> bv512 [256,512)
  hipLaunchKernelGGL(k_dw, dim3(2048, 32), dim3(256), 0, stream, x, w_dw, b_dw, bv512);
  // 8. comb GEMM (K=512, +x residual) -> combT fp16 (d_out; o_r dead); gy=1
  hipLaunchKernelGGL(k_mf8, dim3(64, 1, 8), dim3(512), 0, stream,
                     W16 + WH_COMB, bv512, (size_t)512 * PP, combT, (size_t)CDIM * PP,
                     b_comb, x, (size_t)CDIM * PP, 512);
  // 9. FF chain in batch-quads, descending (combT-in-d_out aliasing safe)
  for (int b = 4; b >= 0; b -= 4) {
    hipLaunchKernelGGL(k_mf8, dim3(64, 4, 4), dim3(512), 0, stream,
                       W16 + WH_FF1, combT + (size_t)b * CDIM * PP, (size_t)CDIM * PP,
                       h1, (size_t)FFI * PP, b_ff1,
                       (const float*)nullptr, (size_t)0, 256);
    hipLaunchKernelGGL(k_ff_fused, dim3(FFI, 4), dim3(256), 0, stream,
                       h1, w_ffdw, b_ffdw, h1);
    hipLaunchKernelGGL(k_mf, dim3(64, 2, 4), dim3(256), 0, stream,
                       W16 + WH_FF2, h1, (size_t)FFI * PP,
                       (f16*)nullptr, outF + (size_t)b * CDIM * PP, (size_t)CDIM * PP,
                       b_ff2, (const float*)nullptr, (size_t)0, 1024);
  }
  // 10. final inorm in place on d_out
  hipLaunchKernelGGL(k_istats, dim3(2048), dim3(256), 0, stream, outF, stm, str);
  hipLaunchKernelGGL(k_napply, dim3(65536), dim3(256), 0, stream, outF, stm, str);
}

// Round 8
// 857.158 us; speedup vs baseline: 1.4254x; 1.0505x over previous
//
#include <hip/hip_runtime.h>
#include <hip/hip_fp16.h>
#include <math.h>

#define B_    8
#define CDIM  256
#define HH    256
#define WW    32
#define PP    8192
#define HEADS 8
#define FFI   1024

typedef _Float16 f16;
typedef _Float16 half8 __attribute__((ext_vector_type(8)));
typedef _Float16 half4 __attribute__((ext_vector_type(4)));
typedef _Float16 f16x2v __attribute__((ext_vector_type(2)));
typedef float f32x4 __attribute__((ext_vector_type(4)));

// soft barrier: LDS-only fence. Drains ds ops (lgkmcnt) but lets register-
// destined global prefetch loads stay in flight across the barrier.
#define SOFT_BARRIER() asm volatile("s_waitcnt lgkmcnt(0)\n\ts_barrier" ::: "memory")

// ---------------- workspace layout (float offsets) ----------------
static const size_t OFF_PPART  = 16777216;   // 64*64*32 f32 = 131072 floats (probe partials)
static const size_t OFF_QPROBE = 16908288;
static const size_t OFF_SH     = 16910336;
static const size_t OFF_IH     = 16912384;
static const size_t OFF_IW     = 16912896;
static const size_t OFF_STM    = 16913408;
static const size_t OFF_STR    = 16921600;
static const size_t OFF_VSEL   = 16929792;
static const size_t OFF_W16    = 17060864;   // 917504 halves = 458752 floats

// fp16 weight region offsets (in halves)
#define WH_QKV  0
#define WH_OUT  196608
#define WH_COMB 262144
#define WH_FF1  393216
#define WH_FF2  655360

// fast gelu: x*Phi(x) via A&S 7.1.26 erf, |erf err| <= 1.5e-7, branchless.
__device__ __forceinline__ float gelu_f(float x) {
  float z = fabsf(x) * 0.70710678118f;
  float t = __builtin_amdgcn_rcpf(1.0f + 0.3275911f * z);
  float poly = t * (0.254829592f +
               t * (-0.284496736f +
               t * (1.421413741f +
               t * (-1.453152027f +
               t * 1.061405429f))));
  float e = 1.0f - poly * __expf(-z * z);
  return 0.5f * x * (1.0f + copysignf(e, x));
}

// ---------------- weights -> fp16 ----------------
__global__ __launch_bounds__(256) void k_wcvt(const float* __restrict__ s0,
                                              const float* __restrict__ s1,
                                              const float* __restrict__ s2,
                                              const float* __restrict__ s3,
                                              const float* __restrict__ s4,
                                              f16* __restrict__ dst) {
  int blk = blockIdx.x;   // 896 blocks x 1024 elems
  const float* src; size_t base;
  if (blk < 192)      { src = s0; base = WH_QKV;  }
  else if (blk < 256) { src = s1; base = WH_OUT;  blk -= 192; }
  else if (blk < 384) { src = s2; base = WH_COMB; blk -= 256; }
  else if (blk < 640) { src = s3; base = WH_FF1;  blk -= 384; }
  else                { src = s4; base = WH_FF2;  blk -= 640; }
  int off = blk * 1024 + threadIdx.x * 4;
  float4 v = *(const float4*)(src + off);
  half4 h; h[0] = (f16)v.x; h[1] = (f16)v.y; h[2] = (f16)v.z; h[3] = (f16)v.w;
  *(half4*)(dst + base + off) = h;
}

// ---------------- fused channel-LN -> xn fp16 ----------------
__global__ __launch_bounds__(256) void k_lnxn(const float* __restrict__ x,
                                              const float* __restrict__ g,
                                              const float* __restrict__ bb,
                                              f16* __restrict__ xn) {
  int idx = blockIdx.x * 256 + threadIdx.x;      // 65536 = b*PP + p
  int b = idx >> 13, p = idx & 8191;
  const float* xp = x + (size_t)b * CDIM * PP + p;
  float s = 0.f, s2 = 0.f;
  for (int c = 0; c < CDIM; c++) { float v = xp[(size_t)c * PP]; s += v; s2 += v * v; }
  float m = s * (1.0f / CDIM);
  float var = s2 * (1.0f / CDIM) - m * m;
  float r = rsqrtf(var + 1e-5f);
  f16* xo = xn + (size_t)b * CDIM * PP + p;
  for (int c = 0; c < CDIM; c++)
    xo[(size_t)c * PP] = (f16)((xp[(size_t)c * PP] - m) * r * g[c] + bb[c]);
}

// ================= MFMA fp16 GEMM, 1-m-tile 256-thread (FF2 float-out) =================
#define MF_STAGE                                                                   \
  int t = threadIdx.x;                                                             \
  int nw_ = gridDim.x * gridDim.y;                                                 \
  int hb_ = blockIdx.x + gridDim.x * blockIdx.y;                                   \
  int wk_ = (hb_ & 7) * (nw_ >> 3) + (hb_ >> 3);                                   \
  int gy_ = gridDim.y;                                                             \
  int sh_ = __ffs(gy_) - 1;                                                        \
  int p0 = (wk_ >> sh_) * 128, m0 = (wk_ & (gy_ - 1)) * 128, z = blockIdx.z;       \
  int lane = t & 63, wave = t >> 6;                                                \
  int wm = (wave >> 1) * 64, wp = (wave & 1) * 64;                                 \
  int col = lane & 15, quad = lane >> 4;                                           \
  f32x4 acc[4][4];                                                                 \
  _Pragma("unroll") for (int i = 0; i < 4; i++)                                    \
  _Pragma("unroll") for (int j = 0; j < 4; j++)                                    \
      acc[i][j] = (f32x4){0.f, 0.f, 0.f, 0.f};                                     \
  int am = t >> 1, ak = (t & 1) * 16;                                              \
  int bp = (t & 15) * 8, bk = (t >> 4) * 2;                                        \
  int erot = t & 7;                                                                \
  const f16* wr0 = W + (size_t)(m0 + am) * K + ak;                                 \
  const f16* br0 = inB + (size_t)bk * PP + p0 + bp;                                \
  half8 w0 = *(const half8*)wr0;                                                   \
  half8 w1 = *(const half8*)(wr0 + 8);                                             \
  half8 r0 = *(const half8*)br0;                                                   \
  half8 r1 = *(const half8*)(br0 + PP);                                            \
  for (int k0 = 0; k0 < K; k0 += 32) {                                             \
    *(half8*)&As[am][ak] = w0;                                                     \
    *(half8*)&As[am][ak + 8] = w1;                                                 \
    _Pragma("unroll") for (int e0 = 0; e0 < 8; e0++) {                             \
      int e = (e0 + erot) & 7;                                                     \
      f16x2v pr2; pr2[0] = r0[e]; pr2[1] = r1[e];                                  \
      *(f16x2v*)&Bs[bp + e][bk] = pr2;                                             \
    }                                                                              \
    SOFT_BARRIER();                                                                \
    int kn = (k0 + 32 < K) ? k0 + 32 : k0;                                         \
    w0 = *(const half8*)(wr0 + kn);                                                \
    w1 = *(const half8*)(wr0 + kn + 8);                                            \
    r0 = *(const half8*)(inB + (size_t)(kn + bk) * PP + p0 + bp);                  \
    r1 = *(const half8*)(inB + (size_t)(kn + bk + 1) * PP + p0 + bp);              \
    half8 af[4], bf[4];                                                            \
    _Pragma("unroll") for (int i = 0; i < 4; i++)                                  \
      af[i] = *(const half8*)&As[wm + i * 16 + col][quad * 8];                     \
    _Pragma("unroll") for (int j = 0; j < 4; j++)                                  \
      bf[j] = *(const half8*)&Bs[wp + j * 16 + col][quad * 8];                     \
    _Pragma("unroll") for (int i = 0; i < 4; i++)                                  \
    _Pragma("unroll") for (int j = 0; j < 4; j++)                                  \
        acc[i][j] = __builtin_amdgcn_mfma_f32_16x16x32_f16(af[i], bf[j],           \
                                                           acc[i][j], 0, 0, 0);    \
    SOFT_BARRIER();                                                                \
  }

__global__ __launch_bounds__(256) void k_mf(const f16* __restrict__ W,
                                            const f16* __restrict__ In, size_t inZ,
                                            f16* __restrict__ OutH,
                                            float* __restrict__ OutF, size_t outZ,
                                            const float* __restrict__ bias,
                                            const float* __restrict__ resid, size_t residZ,
                                            int K) {
  __shared__ f16 As[128][40];
  __shared__ f16 Bs[128][40];
  const f16* inB = In + (size_t)blockIdx.z * inZ;
  MF_STAGE
#pragma unroll
  for (int i = 0; i < 4; i++) {
    int mb = m0 + wm + i * 16 + quad * 4;
#pragma unroll
    for (int r = 0; r < 4; r++) {
      int m = mb + r;
      float bs = bias ? bias[m] : 0.f;
#pragma unroll
      for (int j = 0; j < 4; j++) {
        int p = p0 + wp + j * 16 + col;
        float v = acc[i][j][r] + bs;
        size_t off = (size_t)z * outZ + (size_t)m * PP + p;
        if (resid) v += resid[(size_t)z * residZ + (size_t)m * PP + p];
        if (OutF) OutF[off] = v;
        else OutH[off] = (f16)v;
      }
    }
  }
}

// ========== 8-wave MFMA GEMM: 256m x 128p per block, 512 threads ==========
#define MF_STAGE8                                                                  \
  int t = threadIdx.x;                                                             \
  int nw_ = gridDim.x * gridDim.y;                                                 \
  int hb_ = blockIdx.x + gridDim.x * blockIdx.y;                                   \
  int wk_ = (hb_ & 7) * (nw_ >> 3) + (hb_ >> 3);                                   \
  int gy_ = gridDim.y;                                                             \
  int sh_ = __ffs(gy_) - 1;                                                        \
  int p0 = (wk_ >> sh_) * 128, m0 = (wk_ & (gy_ - 1)) * 256, z = blockIdx.z;       \
  int lane = t & 63, wave = t >> 6;                                                \
  int wm = (wave >> 1) * 64, wp = (wave & 1) * 64;                                 \
  int col = lane & 15, quad = lane >> 4;                                           \
  f32x4 acc[4][4];                                                                 \
  _Pragma("unroll") for (int i = 0; i < 4; i++)                                    \
  _Pragma("unroll") for (int j = 0; j < 4; j++)                                    \
      acc[i][j] = (f32x4){0.f, 0.f, 0.f, 0.f};                                     \
  int am = t >> 1, ak = (t & 1) * 16;                                              \
  int bp = (t & 15) * 8, bk = (t >> 4) * 2;   /* B-staging valid for t<256 */      \
  int erot = t & 7;                                                                \
  const f16* wr0 = W + (size_t)(m0 + am) * K + ak;                                 \
  const f16* br0 = inB + (size_t)(bk & 31) * PP + p0 + bp;                         \
  half8 w0 = *(const half8*)wr0;                                                   \
  half8 w1 = *(const half8*)(wr0 + 8);                                             \
  half8 r0 = {}, r1 = {};                                                          \
  if (t < 256) { r0 = *(const half8*)br0; r1 = *(const half8*)(br0 + PP); }        \
  for (int k0 = 0; k0 < K; k0 += 32) {                                             \
    *(half8*)&As[am][ak] = w0;                                                     \
    *(half8*)&As[am][ak + 8] = w1;                                                 \
    if (t < 256) {                                                                 \
      _Pragma("unroll") for (int e0 = 0; e0 < 8; e0++) {                           \
        int e = (e0 + erot) & 7;                                                   \
        f16x2v pr2; pr2[0] = r0[e]; pr2[1] = r1[e];                                \
        *(f16x2v*)&Bs[bp + e][bk] = pr2;                                           \
      }                                                                            \
    }                                                                              \
    SOFT_BARRIER();                                                                \
    int kn = (k0 + 32 < K) ? k0 + 32 : k0;                                         \
    w0 = *(const half8*)(wr0 + kn);                                                \
    w1 = *(const half8*)(wr0 + kn + 8);                                            \
    if (t < 256) {                                                                 \
      r0 = *(const half8*)(inB + (size_t)(kn + bk) * PP + p0 + bp);                \
      r1 = *(const half8*)(inB + (size_t)(kn + bk + 1) * PP + p0 + bp);            \
    }                                                                              \
    half8 af[4], bf[4];                                                            \
    _Pragma("unroll") for (int i = 0; i < 4; i++)                                  \
      af[i] = *(const half8*)&As[wm + i * 16 + col][quad * 8];                     \
    _Pragma("unroll") for (int j = 0; j < 4; j++)                                  \
      bf[j] = *(const half8*)&Bs[wp + j * 16 + col][quad * 8];                     \
    _Pragma("unroll") for (int i = 0; i < 4; i++)                                  \
    _Pragma("unroll") for (int j = 0; j < 4; j++)                                  \
        acc[i][j] = __builtin_amdgcn_mfma_f32_16x16x32_f16(af[i], bf[j],           \
                                                           acc[i][j], 0, 0, 0);    \
    SOFT_BARRIER();                                                                \
  }

__global__ __launch_bounds__(512) void k_mf8(const f16* __restrict__ W,
                                             const f16* __restrict__ In, size_t inZ,
                                             f16* __restrict__ OutH, size_t outZ,
                                             const float* __restrict__ bias,
                                             const float* __restrict__ resid, size_t residZ,
                                             int K) {
  __shared__ f16 As[256][40];
  __shared__ f16 Bs[128][40];
  const f16* inB = In + (size_t)blockIdx.z * inZ;
  MF_STAGE8
#pragma unroll
  for (int i = 0; i < 4; i++) {
    int mb = m0 + wm + i * 16 + quad * 4;   // wm spans 0..192 across 8 waves
#pragma unroll
    for (int r = 0; r < 4; r++) {
      int m = mb + r;
      float bs = bias ? bias[m] : 0.f;
#pragma unroll
      for (int j = 0; j < 4; j++) {
        int p = p0 + wp + j * 16 + col;
        float v = acc[i][j][r] + bs;
        size_t off = (size_t)z * outZ + (size_t)m * PP + p;
        if (resid) v += resid[(size_t)z * residZ + (size_t)m * PP + p];
        OutH[off] = (f16)v;
      }
    }
  }
}

// qk GEMM (8-wave): epilogue l2-normalizes groups of 32 consecutive p, stores fp16
__global__ __launch_bounds__(512) void k_mf_qk8(const f16* __restrict__ W,
                                                const f16* __restrict__ In, size_t inZ,
                                                f16* __restrict__ qkO, int K) {
  __shared__ f16 As[256][40];
  __shared__ f16 Bs[128][40];
  const f16* inB = In + (size_t)blockIdx.z * inZ;
  MF_STAGE8
#pragma unroll
  for (int i = 0; i < 4; i++) {
    int mb = m0 + wm + i * 16 + quad * 4;
#pragma unroll
    for (int r = 0; r < 4; r++) {
      int m = mb + r;
      size_t base = (size_t)z * 512 * PP + (size_t)m * PP;
#pragma unroll
      for (int jp = 0; jp < 2; jp++) {
        float a0 = acc[i][2 * jp][r], a1 = acc[i][2 * jp + 1][r];
        float ss = a0 * a0 + a1 * a1;
        ss += __shfl_xor(ss, 1);
        ss += __shfl_xor(ss, 2);
        ss += __shfl_xor(ss, 4);
        ss += __shfl_xor(ss, 8);
        float inv = 1.0f / fmaxf(sqrtf(ss), 1e-12f);
        int pa = p0 + wp + 2 * jp * 16 + col;
        qkO[base + pa] = (f16)(a0 * inv);
        qkO[base + pa + 16] = (f16)(a1 * inv);
      }
    }
  }
}

// ---------------- probe partials: one block per (bh, row) ----------------
__global__ __launch_bounds__(256) void k_psum(const f16* __restrict__ qk,
                                              float* __restrict__ part) {
  __shared__ float red[64][32];
  int bh = blockIdx.x, y = blockIdx.y;
  int b = bh >> 3, hd = bh & 7;
  int t = threadIdx.x;
  int row = (y < 32) ? (b * 512 + hd * 32 + y)
                     : (b * 512 + 256 + hd * 32 + (y - 32));
  const f16* rp = qk + (size_t)row * PP;
  int g = t >> 2, w8 = (t & 3) * 8;
  float s[8];
#pragma unroll
  for (int e = 0; e < 8; e++) s[e] = 0.f;
  for (int h = g; h < 256; h += 64) {
    half8 v = *(const half8*)(rp + h * 32 + w8);
#pragma unroll
    for (int e = 0; e < 8; e++) s[e] += (float)v[e];
  }
#pragma unroll
  for (int e = 0; e < 8; e++) red[g][w8 + e] = s[e];
  __syncthreads();
  if (t < 32) {
    float a = 0.f;
    for (int gg = 0; gg < 64; gg++) a += red[gg][t];
    part[((size_t)bh * 64 + y) * 32 + t] = a;
  }
}

// ---------------- probe finish: qp, sh = qp . ksum, top-k(8) ----------------
__global__ __launch_bounds__(64) void k_pfin(const float* __restrict__ part,
                                             float* __restrict__ qprobe,
                                             int* __restrict__ ih) {
  __shared__ float qps[32], shs[32];
  int bh = blockIdx.x, t = threadIdx.x;
  const float* pb = part + (size_t)bh * 2048;
  if (t < 32) {
    float a = 0.f;
    for (int d = 0; d < 32; d++) a += pb[d * 32 + t];
    qps[t] = a;
    qprobe[bh * 32 + t] = a;
  }
  __syncthreads();
  if (t < 32) {
    float a = 0.f;
    const float* kp = pb + (size_t)(32 + t) * 32;
    for (int w = 0; w < 32; w++) a += qps[w] * kp[w];
    shs[t] = a;
  }
  __syncthreads();
  if (t == 0) {
    for (int s = 0; s < 8; s++) {
      int bi = 0; float bv = shs[0];
      for (int i = 1; i < 32; i++) { if (shs[i] > bv) { bv = shs[i]; bi = i; } }
      ih[bh * 8 + s] = bi;
      shs[bi] = -3.4e38f;
    }
  }
}

__global__ __launch_bounds__(256) void k_sw_topk(const f16* __restrict__ qk,
                                                 const float* __restrict__ qprobe,
                                                 const int* __restrict__ ih,
                                                 int* __restrict__ iw) {
  __shared__ float qp[32];
  __shared__ float sw[256];
  __shared__ int ihs[8];
  int bh = blockIdx.x, b = bh >> 3, hd = bh & 7;
  int t = threadIdx.x;
  if (t < 32) qp[t] = qprobe[bh * 32 + t];
  if (t < 8) ihs[t] = ih[bh * 8 + t];
  __syncthreads();
  const f16* kb = qk + ((size_t)(b * 512 + 256 + hd * 32)) * PP;
  float s = 0.f;
  for (int a = 0; a < 8; a++) {
    const f16* kd = kb + (size_t)ihs[a] * PP + t * 32;
#pragma unroll
    for (int w = 0; w < 32; w++) s += qp[w] * (float)kd[w];
  }
  sw[t] = s;
  __syncthreads();
  if (t == 0) {
    for (int sel = 0; sel < 8; sel++) {
      int bi = 0; float bv = sw[0];
      for (int i = 1; i < 256; i++) { if (sw[i] > bv) { bv = sw[i]; bi = i; } }
      iw[bh * 8 + sel] = bi;
      sw[bi] = -3.4e38f;
    }
  }
}

// ---------------- v at selected positions, LDS-staged from xn fp16 ----------------
__global__ __launch_bounds__(256) void k_vsel2(const f16* __restrict__ xn,
                                               const f16* __restrict__ W16,
                                               const int* __restrict__ ih,
                                               const int* __restrict__ iw,
                                               float* __restrict__ vsel) {
  __shared__ f16 xg[64][264];
  __shared__ float wrow[8][64];
  __shared__ int ihs[8], iws8[8];
  int bh = blockIdx.x, b = bh >> 3, hd = bh & 7;
  int t = threadIdx.x;
  if (t < 8) { ihs[t] = ih[bh * 8 + t]; iws8[t] = iw[bh * 8 + t]; }
  __syncthreads();
  float acc[8];
#pragma unroll
  for (int a = 0; a < 8; a++) acc[a] = 0.f;
  for (int c0 = 0; c0 < 256; c0 += 64) {
    for (int rep = 0; rep < 2; rep++) {
      int cc = rep * 32 + (t >> 3);
      int seg = t & 7;
#pragma unroll
      for (int u = 0; u < 4; u++) {
        int h8 = seg * 4 + u;                 // 0..31
        int bi = h8 >> 2, wq = (h8 & 3) * 8;
        half8 v = *(const half8*)(xn + ((size_t)(b * 256 + c0 + cc)) * PP + iws8[bi] * 32 + wq);
        *(half8*)&xg[cc][h8 * 8] = v;
      }
    }
    for (int rep = 0; rep < 2; rep++) {
      int idx = t + rep * 256;
      int a = idx >> 6, cc = idx & 63;
      wrow[a][cc] = (float)W16[(size_t)(512 + hd * 32 + ihs[a]) * 256 + c0 + cc];
    }
    __syncthreads();
    for (int cc = 0; cc < 64; cc++) {
      float xv = (float)xg[cc][t];
#pragma unroll
      for (int a = 0; a < 8; a++) acc[a] += wrow[a][cc] * xv;
    }
    __syncthreads();
  }
  int bi = t >> 5, w = t & 31;
#pragma unroll
  for (int a = 0; a < 8; a++)
    vsel[((size_t)bh * 64 + a * 8 + bi) * 32 + w] = acc[a];
}

// ---------------- MFMA attention ----------------
__global__ __launch_bounds__(256) void k_attn_mf(const f16* __restrict__ qk,
                                                 const float* __restrict__ vsel,
                                                 const int* __restrict__ ih,
                                                 const int* __restrict__ iw,
                                                 f16* __restrict__ o_r) {
  __shared__ f16 Ks[64][40];
  __shared__ f16 Vt[32][72];
  __shared__ f16 Ps[4][32][72];
  __shared__ f16 Os[32][136];
  __shared__ int ihs[8], iws8[8];
  int bh = blockIdx.y, b = bh >> 3, hd = bh & 7;
  int t = threadIdx.x;
  if (t < 8) { ihs[t] = ih[bh * 8 + t]; iws8[t] = iw[bh * 8 + t]; }
  __syncthreads();
  {
    int j = t >> 2, wc = (t & 3) * 8;
    const f16* kb = qk + ((size_t)(b * 512 + 256 + hd * 32 + ihs[j >> 3])) * PP
                    + iws8[j & 7] * 32 + wc;
    *(half8*)&Ks[j][wc] = *(const half8*)kb;
  }
  for (int rep = 0; rep < 2; rep++) {
    int idx = t + rep * 256;
    int j = idx >> 3, w4 = (idx & 7) * 4;
    float4 v = *(const float4*)(vsel + ((size_t)bh * 64 + j) * 32 + w4);
    Vt[w4 + 0][j] = (f16)v.x; Vt[w4 + 1][j] = (f16)v.y;
    Vt[w4 + 2][j] = (f16)v.z; Vt[w4 + 3][j] = (f16)v.w;
  }
  __syncthreads();
  int wv = t >> 6, lane = t & 63, col = lane & 15, quad = lane >> 4;
  int i0 = blockIdx.x * 128;
  int dq = i0 >> 8;
  int hb = (i0 & 255) + wv * 32;
  const f16* qbase = qk + ((size_t)(b * 512 + hd * 32 + dq)) * PP;
  f32x4 sacc[2][4];
#pragma unroll
  for (int i = 0; i < 2; i++)
#pragma unroll
    for (int j = 0; j < 4; j++) sacc[i][j] = (f32x4){0.f, 0.f, 0.f, 0.f};
#pragma unroll
  for (int mt = 0; mt < 2; mt++) {
    half8 af = *(const half8*)(qbase + (size_t)(hb + mt * 16 + col) * 32 + quad * 8);
#pragma unroll
    for (int nt = 0; nt < 4; nt++) {
      half8 bf = *(const half8*)&Ks[nt * 16 + col][quad * 8];
      sacc[mt][nt] = __builtin_amdgcn_mfma_f32_16x16x32_f16(af, bf, sacc[mt][nt], 0, 0, 0);
    }
  }
#pragma unroll
  for (int mt = 0; mt < 2; mt++) {
#pragma unroll
    for (int r = 0; r < 4; r++) {
      float s0 = sacc[mt][0][r], s1 = sacc[mt][1][r], s2 = sacc[mt][2][r], s3 = sacc[mt][3][r];
      float mx = fmaxf(fmaxf(s0, s1), fmaxf(s2, s3));
      mx = fmaxf(mx, __shfl_xor(mx, 1));
      mx = fmaxf(mx, __shfl_xor(mx, 2));
      mx = fmaxf(mx, __shfl_xor(mx, 4));
      mx = fmaxf(mx, __shfl_xor(mx, 8));
      float e0 = __expf(s0 - mx), e1 = __expf(s1 - mx), e2 = __expf(s2 - mx), e3 = __expf(s3 - mx);
      float l = e0 + e1 + e2 + e3;
      l += __shfl_xor(l, 1);
      l += __shfl_xor(l, 2);
      l += __shfl_xor(l, 4);
      l += __shfl_xor(l, 8);
      float inv = 1.0f / l;
      int row = mt * 16 + quad * 4 + r;
      Ps[wv][row][0 * 16 + col] = (f16)(e0 * inv);
      Ps[wv][row][1 * 16 + col] = (f16)(e1 * inv);
      Ps[wv][row][2 * 16 + col] = (f16)(e2 * inv);
      Ps[wv][row][3 * 16 + col] = (f16)(e3 * inv);
    }
  }
  __syncthreads();
  f32x4 oacc[2][2];
#pragma unroll
  for (int i = 0; i < 2; i++)
#pragma unroll
    for (int j = 0; j < 2; j++) oacc[i][j] = (f32x4){0.f, 0.f, 0.f, 0.f};
#pragma unroll
  for (int kk = 0; kk < 2; kk++) {
    half8 ap[2], bv[2];
#pragma unroll
    for (int mt = 0; mt < 2; mt++) ap[mt] = *(const half8*)&Ps[wv][mt * 16 + col][kk * 32 + quad * 8];
#pragma unroll
    for (int wn = 0; wn < 2; wn++) bv[wn] = *(const half8*)&Vt[wn * 16 + col][kk * 32 + quad * 8];
#pragma unroll
    for (int mt = 0; mt < 2; mt++)
#pragma unroll
      for (int wn = 0; wn < 2; wn++)
        oacc[mt][wn] = __builtin_amdgcn_mfma_f32_16x16x32_f16(ap[mt], bv[wn], oacc[mt][wn], 0, 0, 0);
  }
#pragma unroll
  for (int mt = 0; mt < 2; mt++)
#pragma unroll
    for (int wn = 0; wn < 2; wn++)
#pragma unroll
      for (int r = 0; r < 4; r++)
        Os[wn * 16 + col][wv * 32 + mt * 16 + quad * 4 + r] = (f16)oacc[mt][wn][r];
  __syncthreads();
  {
    int dd = t >> 3, seg = t & 7;
#pragma unroll
    for (int u = 0; u < 2; u++) {
      int io = (seg * 2 + u) * 8;
      *(half8*)(o_r + ((size_t)(b * 256 + hd * 32 + dd)) * PP + i0 + io) = *(const half8*)&Os[dd][io];
    }
  }
}

// ---------------- conv branch dw3x3 on x -> fp16 channels [256,512) of bv512 ----------------
__global__ __launch_bounds__(256) void k_dw(const float* __restrict__ in,
                                            const float* __restrict__ wdw,
                                            const float* __restrict__ bdw,
                                            f16* __restrict__ out) {
  int bc = blockIdx.x;
  int b = bc >> 8, c = bc & 255;
  int p = blockIdx.y * 256 + threadIdx.x;
  int x0 = p >> 5, y0 = p & 31;
  const float* ip = in + (size_t)bc * PP;
  const float* wp = wdw + c * 9;
  float s = bdw[c];
#pragma unroll
  for (int i = 0; i < 3; i++) {
    int xx = x0 + i - 1;
    if (xx < 0 || xx >= HH) continue;
#pragma unroll
    for (int j = 0; j < 3; j++) {
      int yy = y0 + j - 1;
      if (yy < 0 || yy >= WW) continue;
      s += wp[i * 3 + j] * ip[xx * 32 + yy];
    }
  }
  out[((size_t)(b * 512 + 256 + c)) * PP + p] = (f16)s;
}

// ======== fused FF inner v4: transposed f16 LDS planes, low VGPR/LDS ========
// gc[y][x]: plane y (0..31 = W), x (0..255 = H), plane stride 266 halves
// -> phase2/5 accesses cover all 32 banks (conflict-free); conv reads are
// lane-consecutive. In-place safe (h2 may alias h1).
__global__ __launch_bounds__(256) void k_ff_fused(const f16* __restrict__ h1,
                                                  const float* __restrict__ wdw,
                                                  const float* __restrict__ bdw,
                                                  f16* __restrict__ h2) {
  __shared__ f16 gc[32 * 266];
  __shared__ float redA[8], redB[8];
  int c = blockIdx.x, zz = blockIdx.y;
  int t = threadIdx.x;
  int wv = t >> 6, lane = t & 63;
  const f16* hp = h1 + ((size_t)zz * FFI + c) * PP;
  f16* out = h2 + ((size_t)zz * FFI + c) * PP;

  // phase 1: coalesced load (v in regs), raw stats via wave reduce
  float v[32];
  {
    float s = 0.f, s2 = 0.f;
#pragma unroll
    for (int u = 0; u < 4; u++) {
      half8 h = *(const half8*)(hp + (u * 256 + t) * 8);
#pragma unroll
      for (int e = 0; e < 8; e++) { float f = (float)h[e]; v[u * 8 + e] = f; s += f; s2 += f * f; }
    }
#pragma unroll
    for (int o = 32; o; o >>= 1) { s += __shfl_xor(s, o); s2 += __shfl_xor(s2, o); }
    if (lane == 0) { redA[wv] = s; redA[4 + wv] = s2; }
  }
  __syncthreads();
  float m = (redA[0] + redA[1] + redA[2] + redA[3]) * (1.0f / PP);
  float s2a = (redA[4] + redA[5] + redA[6] + redA[7]) * (1.0f / PP);
  float r = rsqrtf(s2a - m * m + 1e-5f);

  // phase 2: g = gelu(inorm(v)) -> f16 planes (x = u*64 + t>>2, y = (t&3)*8+e)
  {
    int xq = t >> 2, yb = (t & 3) * 8;
#pragma unroll
    for (int u = 0; u < 4; u++) {
      int x = u * 64 + xq;
#pragma unroll
      for (int e = 0; e < 8; e++)
        gc[(yb + e) * 266 + x] = (f16)gelu_f((v[u * 8 + e] - m) * r);
    }
  }
  __syncthreads();

  // phase 3: conv 3x3; thread t owns column x=t (spatial row t), sliding 9-window
  float wf[9];
#pragma unroll
  for (int i = 0; i < 9; i++) wf[i] = wdw[c * 9 + i];
  float bd = bdw[c];
  bool hasL = (t > 0), hasR = (t < 255);
  float d[32];
  float sd = 0.f, sd2 = 0.f;
  float am1 = 0.f, a0, ap1, bm1 = 0.f, b0, bp1, cm1 = 0.f, c0, cp1;
  a0 = hasL ? (float)gc[t - 1] : 0.f;
  b0 = (float)gc[t];
  c0 = hasR ? (float)gc[t + 1] : 0.f;
#pragma unroll
  for (int y = 0; y < 32; y++) {
    if (y < 31) {
      ap1 = hasL ? (float)gc[(y + 1) * 266 + t - 1] : 0.f;
      bp1 = (float)gc[(y + 1) * 266 + t];
      cp1 = hasR ? (float)gc[(y + 1) * 266 + t + 1] : 0.f;
    } else { ap1 = 0.f; bp1 = 0.f; cp1 = 0.f; }
    float a = bd + wf[0] * am1 + wf[1] * a0 + wf[2] * ap1
                 + wf[3] * bm1 + wf[4] * b0 + wf[5] * bp1
                 + wf[6] * cm1 + wf[7] * c0 + wf[8] * cp1;
    d[y] = a; sd += a; sd2 += a * a;
    am1 = a0; a0 = ap1; bm1 = b0; b0 = bp1; cm1 = c0; c0 = cp1;
  }
  // phase 4 stats: wave reduce
#pragma unroll
  for (int o = 32; o; o >>= 1) { sd += __shfl_xor(sd, o); sd2 += __shfl_xor(sd2, o); }
  if (lane == 0) { redB[wv] = sd; redB[4 + wv] = sd2; }
  __syncthreads();
  float dm = (redB[0] + redB[1] + redB[2] + redB[3]) * (1.0f / PP);
  float dv = (redB[4] + redB[5] + redB[6] + redB[7]) * (1.0f / PP);
  float dr = rsqrtf(dv - dm * dm + 1e-5f);

  // phase 4b: h2 = g + gelu(inorm(d)); thread reads/writes ONLY its own column
#pragma unroll
  for (int y = 0; y < 32; y++) {
    float gt = (float)gc[y * 266 + t];
    gc[y * 266 + t] = (f16)(gt + gelu_f((d[y] - dm) * dr));
  }
  __syncthreads();

  // phase 5: coalesced store (same mapping as phase 2)
  {
    int xq = t >> 2, yb = (t & 3) * 8;
#pragma unroll
    for (int u = 0; u < 4; u++) {
      int x = u * 64 + xq;
      half8 h;
#pragma unroll
      for (int e = 0; e < 8; e++) h[e] = gc[(yb + e) * 266 + x];
      *(half8*)(out + (u * 256 + t) * 8) = h;
    }
  }
}

// ---------------- fp32 inorm stats + apply (final) ----------------
__global__ __launch_bounds__(256) void k_istats(const float* __restrict__ in,
                                                float* __restrict__ stm,
                                                float* __restrict__ str) {
  __shared__ float ss[256], ss2[256];
  int row = blockIdx.x, t = threadIdx.x;
  const float* p = in + (size_t)row * PP;
  float s = 0.f, s2 = 0.f;
  for (int i = t; i < PP; i += 256) { float v = p[i]; s += v; s2 += v * v; }
  ss[t] = s; ss2[t] = s2;
  __syncthreads();
  for (int off = 128; off; off >>= 1) {
    if (t < off) { ss[t] += ss[t + off]; ss2[t] += ss2[t + off]; }
    __syncthreads();
  }
  if (t == 0) {
    float m = ss[0] * (1.0f / PP);
    float var = ss2[0] * (1.0f / PP) - m * m;
    stm[row] = m;
    str[row] = rsqrtf(var + 1e-5f);
  }
}

__global__ __launch_bounds__(256) void k_napply(float* __restrict__ io,
                                                const float* __restrict__ stm,
                                                const float* __restrict__ str) {
  size_t idx = (size_t)blockIdx.x * 256 + threadIdx.x;
  int row = (int)(idx >> 13);
  io[idx] = (io[idx] - stm[row]) * str[row];
}

extern "C" void kernel_launch(void* const* d_in, const int* in_sizes, int n_in,
                              void* d_out, int out_size, void* d_ws, size_t ws_size,
                              hipStream_t stream) {
  const float* x      = (const float*)d_in[0];
  const float* cln_g  = (const float*)d_in[1];
  const float* cln_b  = (const float*)d_in[2];
  const float* w_qkv  = (const float*)d_in[3];
  const float* w_out  = (const float*)d_in[4];
  const float* b_out  = (const float*)d_in[5];
  const float* w_dw   = (const float*)d_in[6];
  const float* b_dw   = (const float*)d_in[7];
  const float* w_comb = (const float*)d_in[8];
  const float* b_comb = (const float*)d_in[9];
  const float* w_ff1  = (const float*)d_in[10];
  const float* b_ff1  = (const float*)d_in[11];
  const float* w_ffdw = (const float*)d_in[12];
  const float* b_ffdw = (const float*)d_in[13];
  const float* w_ff2  = (const float*)d_in[14];
  const float* b_ff2  = (const float*)d_in[15];
  float* outF = (float*)d_out;

  float* ws = (float*)d_ws;
  f16* qk    = (f16*)ws;
  f16* bv512 = (f16*)ws;
  f16* h1    = (f16*)ws;            // z=4 slab: 1024*8192*4*2B = 64 MiB = BIG
  f16* xn    = (f16*)d_out;
  f16* o_r   = (f16*)d_out;
  f16* combT = (f16*)d_out;
  float* ppart  = ws + OFF_PPART;
  float* qprobe = ws + OFF_QPROBE;
  int*   ih     = (int*)(ws + OFF_IH);
  int*   iw     = (int*)(ws + OFF_IW);
  float* stm    = ws + OFF_STM;
  float* str    = ws + OFF_STR;
  float* vsel   = ws + OFF_VSEL;
  f16*   W16    = (f16*)(ws + OFF_W16);

  // 0. weights -> fp16
  hipLaunchKernelGGL(k_wcvt, dim3(896), dim3(256), 0, stream,
                     w_qkv, w_out, w_comb, w_ff1, w_ff2, W16);
  // 1. fused channel-LN -> xn fp16 (d_out)
  hipLaunchKernelGGL(k_lnxn, dim3(256), dim3(256), 0, stream, x, cln_g, cln_b, xn);
  // 2. q,k GEMM (+l2norm) -> qk fp16 (ws); 8-wave 256m-tile, gy=2 covers M=512
  hipLaunchKernelGGL(k_mf_qk8, dim3(64, 2, 8), dim3(512), 0, stream,
                     W16 + WH_QKV, xn, (size_t)CDIM * PP, qk, 256);
  // 3. probes + top-k (parallelized: 4096-block partial sums + 64-block finish)
  hipLaunchKernelGGL(k_psum, dim3(64, 64), dim3(256), 0, stream, qk, ppart);
  hipLaunchKernelGGL(k_pfin, dim3(64), dim3(64), 0, stream, ppart, qprobe, ih);
  hipLaunchKernelGGL(k_sw_topk, dim3(64), dim3(256), 0, stream, qk, qprobe, ih, iw);
  // 4. v at selected positions (reads xn, still live)
  hipLaunchKernelGGL(k_vsel2, dim3(64), dim3(256), 0, stream, xn, W16 + WH_QKV, ih, iw, vsel);
  // 5. MFMA attention -> o_r fp16 (d_out; xn dead)
  hipLaunchKernelGGL(k_attn_mf, dim3(64, 64), dim3(256), 0, stream, qk, vsel, ih, iw, o_r);
  // 6. attn_branch GEMM -> bv512 [0,256) (qk dead); M=256 -> gy=1
  hipLaunchKernelGGL(k_mf8, dim3(64, 1, 8), dim3(512), 0, stream,
                     W16 + WH_OUT, o_r, (size_t)CDIM * PP, bv512, (size_t)512 * PP,
                     b_out, (const float*)nullptr, (size_t)0, 256);
  // 7. conv branch -> bv512 [256,512)
  hipLaunchKernelGGL(k_dw, dim3(2048, 32), dim3(256), 0, stream, x, w_dw, b_dw, bv512);
  // 8. comb GEMM (K=512, +x residual) -> combT fp16 (d_out; o_r dead); gy=1
  hipLaunchKernelGGL(k_mf8, dim3(64, 1, 8), dim3(512), 0, stream,
                     W16 + WH_COMB, bv512, (size_t)512 * PP, combT, (size_t)CDIM * PP,
                     b_comb, x, (size_t)CDIM * PP, 512);
  // 9. FF chain in batch-quads, descending (combT-in-d_out aliasing safe)
  for (int b = 4; b >= 0; b -= 4) {
    hipLaunchKernelGGL(k_mf8, dim3(64, 4, 4), dim3(512), 0, stream,
                       W16 + WH_FF1, combT + (size_t)b * CDIM * PP, (size_t)CDIM * PP,
                       h1, (size_t)FFI * PP, b_ff1,
                       (const float*)nullptr, (size_t)0, 256);
    hipLaunchKernelGGL(k_ff_fused, dim3(FFI, 4), dim3(256), 0, stream,
                       h1, w_ffdw, b_ffdw, h1);
    hipLaunchKernelGGL(k_mf, dim3(64, 2, 4), dim3(256), 0, stream,
                       W16 + WH_FF2, h1, (size_t)FFI * PP,
                       (f16*)nullptr, outF + (size_t)b * CDIM * PP, (size_t)CDIM * PP,
                       b_ff2, (const float*)nullptr, (size_t)0, 1024);
  }
  // 10. final inorm in place on d_out
  hipLaunchKernelGGL(k_istats, dim3(2048), dim3(256), 0, stream, outF, stm, str);
  hipLaunchKernelGGL(k_napply, dim3(65536), dim3(256), 0, stream, outF, stm, str);
}